// Round 13
// baseline (242.269 us; speedup 1.0000x reference)
//
#include <hip/hip_runtime.h>
#include <cstdint>
#include <cstddef>

#define HIDN 256
#define NHEAD 8
#define HD 32
#define NSEQ 2048
#define QS (0.17677669529663687f * 1.4426950408889634f)   // 1/sqrt(32) * log2(e)

typedef __attribute__((ext_vector_type(8))) short short8;
typedef __attribute__((ext_vector_type(4))) short short4v;
typedef __attribute__((ext_vector_type(4))) float f32x4;
typedef __attribute__((ext_vector_type(16))) float f32x16;
typedef __attribute__((ext_vector_type(4))) uint32_t u32x4;

static __device__ __forceinline__ short f2bf(float f) {
    union { float f; uint32_t u; } v; v.f = f;
    uint32_t r = (v.u + 0x7FFF + ((v.u >> 16) & 1)) >> 16;
    return (short)r;
}
static __device__ __forceinline__ float bf2f(short s) {
    union { uint32_t u; float f; } v; v.u = ((uint32_t)(uint16_t)s) << 16;
    return v.f;
}

// fast exp2: single v_exp_f32 (scores are small here)
static __device__ __forceinline__ float ex2(float x) {
#if defined(__has_builtin)
#if __has_builtin(__builtin_amdgcn_exp2f)
    return __builtin_amdgcn_exp2f(x);
#else
    return exp2f(x);
#endif
#else
    return exp2f(x);
#endif
}

// pack two f32 -> bf16x2 in one instruction (lo in [15:0], hi in [31:16])
static __device__ __forceinline__ uint32_t pkbf16(float lo, float hi) {
    uint32_t r;
    asm("v_cvt_pk_bf16_f32 %0, %1, %2" : "=v"(r) : "v"(lo), "v"(hi));
    return r;
}

// async global->LDS, 16B per lane; LDS dest = wave-uniform base + lane*16
static __device__ __forceinline__ void gload16(const void* g, void* l) {
    __builtin_amdgcn_global_load_lds(
        (__attribute__((address_space(1))) void*)g,
        (__attribute__((address_space(3))) void*)l, 16, 0, 0);
}

static __device__ __forceinline__ f32x16 zero16() {
    f32x16 z;
    #pragma unroll
    for (int i = 0; i < 16; i++) z[i] = 0.f;
    return z;
}

// ---------------------------------------------------------------------------
// Kernel 0: weight conversion (QS folded into Wq, alphas folded into Wg).
// ---------------------------------------------------------------------------
__global__ __launch_bounds__(256) void wcvt_kernel(
    const float* __restrict__ Wq, const float* __restrict__ Wk,
    const float* __restrict__ Wv, const float* __restrict__ Wvec,
    const float* __restrict__ Wo, const float* __restrict__ Wg,
    const float* __restrict__ bq, const float* __restrict__ bk,
    const float* __restrict__ bv,
    const float* __restrict__ ad, const float* __restrict__ an,
    short* __restrict__ Wqkvb, short* __restrict__ Wvecb,
    short* __restrict__ Wob, short* __restrict__ Wgb, float* __restrict__ bqkvs)
{
    int idx = blockIdx.x * 256 + threadIdx.x;
    if (idx < 65536)        Wqkvb[idx] = f2bf(Wq[idx] * QS);
    else if (idx < 131072)  Wqkvb[idx] = f2bf(Wk[idx - 65536]);
    else if (idx < 196608)  Wqkvb[idx] = f2bf(Wv[idx - 131072]);
    else if (idx < 327680)  Wvecb[idx - 196608] = f2bf(Wvec[idx - 196608]);
    else if (idx < 524288)  Wob[idx - 327680] = f2bf(Wo[idx - 327680]);
    else {
        int i2 = idx - 524288;
        int k = i2 & 511;
        float s = (k < 256) ? ad[0] : an[0];
        Wgb[i2] = f2bf(Wg[i2] * s);
    }
    if (idx < 256)          bqkvs[idx] = bq[idx] * QS;
    else if (idx < 512)     bqkvs[idx] = bk[idx - 256];
    else if (idx < 768)     bqkvs[idx] = bv[idx - 512];
}

// ---------------------------------------------------------------------------
// Kernel 1: FUSED prep = qkv + vec in one dispatch, 256-thr blocks.
// Round-11 load-batch + sched_barrier(0) pattern (confirmed: prep left the
// top-5). Blocks 0..1023: vec path. Blocks 1024..1791: qkv path.
//   kbf: [bh][kt(64keys)][frag f=t2*2+ks][lane][8 shorts]
//   vtb: [bh][kt][frag f=dt*4+ks][lane][8 shorts]
// ---------------------------------------------------------------------------
__global__ __launch_bounds__(256) void prep_kernel(
    const float* __restrict__ x, const short* __restrict__ Wqkvb,
    const float* __restrict__ bqkvs, const short* __restrict__ Wvecb,
    short* __restrict__ qbf, short* __restrict__ kbf, short* __restrict__ vtb,
    float* __restrict__ dotb, short* __restrict__ invb, float* __restrict__ normb)
{
    __shared__ __align__(16) short smem[3 * 16 * 264];   // 25.3 KB pool
    const int tid = threadIdx.x;
    const int D = blockIdx.x;

    const int wave = tid >> 6, lane = tid & 63;
    const int col = lane & 15, quad = lane >> 4;

    if (D < 1024) {
        // ================= vec path: 16 tokens x 128 channels =================
        const int half = D & 1;
        const int m0 = (D >> 1) * 16;
        const int b = m0 >> 11, n0 = m0 & 2047;

        #pragma unroll
        for (int p = 0; p < 12; p++) {
            int f4 = p * 256 + tid;
            int t = f4 / 192;
            int rem = f4 - t * 192;
            int c = rem >> 6, j4 = rem & 63;
            float4 v = *(const float4*)(x + (size_t)(m0 + t) * 1024 + 256 + c * 256 + j4 * 4);
            short4v s = { f2bf(v.x), f2bf(v.y), f2bf(v.z), f2bf(v.w) };
            *(short4v*)&smem[(c * 16 + t) * 264 + j4 * 4] = s;
        }
        __syncthreads();

        const int j0 = half * 128 + wave * 32;

        f32x4 d1[3][2], d2[3][2];
        #pragma unroll
        for (int c = 0; c < 3; c++)
            #pragma unroll
            for (int nt = 0; nt < 2; nt++) {
                d1[c][nt] = (f32x4){0.f,0.f,0.f,0.f};
                d2[c][nt] = (f32x4){0.f,0.f,0.f,0.f};
            }

        #pragma unroll
        for (int kk = 0; kk < 8; kk++) {
            // --- issue all loads for this phase (4 global + 3 LDS) ---
            short8 w1a = *(const short8*)&Wvecb[(size_t)(j0 + col) * 256 + kk * 32 + quad * 8];
            short8 w1b = *(const short8*)&Wvecb[(size_t)(j0 + 16 + col) * 256 + kk * 32 + quad * 8];
            short8 w2a = *(const short8*)&Wvecb[(size_t)(256 + j0 + col) * 256 + kk * 32 + quad * 8];
            short8 w2b = *(const short8*)&Wvecb[(size_t)(256 + j0 + 16 + col) * 256 + kk * 32 + quad * 8];
            short8 xf0 = *(const short8*)&smem[(0 * 16 + col) * 264 + kk * 32 + quad * 8];
            short8 xf1 = *(const short8*)&smem[(1 * 16 + col) * 264 + kk * 32 + quad * 8];
            short8 xf2 = *(const short8*)&smem[(2 * 16 + col) * 264 + kk * 32 + quad * 8];
            __builtin_amdgcn_sched_barrier(0);  // loads may NOT sink past here
            // --- consume: 12 MFMAs ---
            d1[0][0] = __builtin_amdgcn_mfma_f32_16x16x32_bf16(w1a, xf0, d1[0][0], 0, 0, 0);
            d1[0][1] = __builtin_amdgcn_mfma_f32_16x16x32_bf16(w1b, xf0, d1[0][1], 0, 0, 0);
            d2[0][0] = __builtin_amdgcn_mfma_f32_16x16x32_bf16(w2a, xf0, d2[0][0], 0, 0, 0);
            d2[0][1] = __builtin_amdgcn_mfma_f32_16x16x32_bf16(w2b, xf0, d2[0][1], 0, 0, 0);
            d1[1][0] = __builtin_amdgcn_mfma_f32_16x16x32_bf16(w1a, xf1, d1[1][0], 0, 0, 0);
            d1[1][1] = __builtin_amdgcn_mfma_f32_16x16x32_bf16(w1b, xf1, d1[1][1], 0, 0, 0);
            d2[1][0] = __builtin_amdgcn_mfma_f32_16x16x32_bf16(w2a, xf1, d2[1][0], 0, 0, 0);
            d2[1][1] = __builtin_amdgcn_mfma_f32_16x16x32_bf16(w2b, xf1, d2[1][1], 0, 0, 0);
            d1[2][0] = __builtin_amdgcn_mfma_f32_16x16x32_bf16(w1a, xf2, d1[2][0], 0, 0, 0);
            d1[2][1] = __builtin_amdgcn_mfma_f32_16x16x32_bf16(w1b, xf2, d1[2][1], 0, 0, 0);
            d2[2][0] = __builtin_amdgcn_mfma_f32_16x16x32_bf16(w2a, xf2, d2[2][0], 0, 0, 0);
            d2[2][1] = __builtin_amdgcn_mfma_f32_16x16x32_bf16(w2b, xf2, d2[2][1], 0, 0, 0);
        }
        #pragma unroll
        for (int nt = 0; nt < 2; nt++) {
            f32x4 dac = d1[0][nt] * d2[0][nt] + d1[1][nt] * d2[1][nt] + d1[2][nt] * d2[2][nt];
            float4 o = { dac[0], dac[1], dac[2], dac[3] };
            *(float4*)&dotb[(size_t)(m0 + col) * 256 + j0 + nt * 16 + quad * 4] = o;
            short4v s = { f2bf(dac[0]), f2bf(dac[1]), f2bf(dac[2]), f2bf(dac[3]) };
            *(short4v*)&invb[(size_t)(m0 + col) * 512 + j0 + nt * 16 + quad * 4] = s;
        }

        const int j = half * 128 + (tid & 127);
        const int tp = tid >> 7;                // 0..1
        #pragma unroll
        for (int t8 = 0; t8 < 8; t8++) {
            int t = tp * 8 + t8;
            float v0 = bf2f(smem[(0 * 16 + t) * 264 + j]);
            float v1 = bf2f(smem[(1 * 16 + t) * 264 + j]);
            float v2 = bf2f(smem[(2 * 16 + t) * 264 + j]);
            float nm = sqrtf(v0 * v0 + v1 * v1 + v2 * v2);
            normb[(size_t)(m0 + t) * 256 + j] = nm;
            invb[(size_t)(m0 + t) * 512 + 256 + j] = f2bf(nm);
        }
        {
            size_t tile = (size_t)(b * 8 + (j >> 5)) * 32 + (n0 >> 6);
            int kbse = (n0 & 63) + tp * 8;
            int ks = kbse >> 4, h2 = (kbse >> 3) & 1;
            #pragma unroll
            for (int c = 0; c < 3; c++) {
                short8 s;
                #pragma unroll
                for (int t8 = 0; t8 < 8; t8++) s[t8] = smem[(c * 16 + tp * 8 + t8) * 264 + j];
                int f = (1 + c) * 4 + ks;           // dt = 1+c
                *(short8*)(vtb + tile * 8192 + f * 512 + ((j & 31) + h2 * 32) * 8) = s;
            }
        }
    } else {
        // ================= qkv path =================
        short* xs   = smem;                     // 32*264 shorts (16.9 KB)
        short* vtmp = smem;                     // 256*34 shorts (17.4 KB) — alias
        const int E = D - 1024;
        const int y = E >> 8;                   // 0..2
        const int m0 = (E & 255) * 32;
        const int b  = m0 >> 11;
        const int n0 = m0 & 2047;

        #pragma unroll
        for (int l = 0; l < 8; l++) {
            int i = l * 256 + tid;
            int t = i >> 6, j4 = i & 63;
            float4 v = *(const float4*)(x + (size_t)(m0 + t) * 1024 + j4 * 4);
            short4v s = { f2bf(v.x), f2bf(v.y), f2bf(v.z), f2bf(v.w) };
            *(short4v*)&xs[t * 264 + j4 * 4] = s;
        }
        __syncthreads();

        f32x4 acc[2][4];
        #pragma unroll
        for (int mt = 0; mt < 2; mt++)
            #pragma unroll
            for (int nt = 0; nt < 4; nt++) acc[mt][nt] = (f32x4){0.f,0.f,0.f,0.f};

        const short* Wb = Wqkvb + (size_t)(y * 256 + wave * 64) * 256;
        #pragma unroll
        for (int kk = 0; kk < 8; kk++) {
            // --- issue all loads for this phase (4 global + 2 LDS) ---
            short8 wf0 = *(const short8*)(Wb + (size_t)(0 * 16 + col) * 256 + kk * 32 + quad * 8);
            short8 wf1 = *(const short8*)(Wb + (size_t)(1 * 16 + col) * 256 + kk * 32 + quad * 8);
            short8 wf2 = *(const short8*)(Wb + (size_t)(2 * 16 + col) * 256 + kk * 32 + quad * 8);
            short8 wf3 = *(const short8*)(Wb + (size_t)(3 * 16 + col) * 256 + kk * 32 + quad * 8);
            short8 xa  = *(const short8*)&xs[(0 * 16 + col) * 264 + kk * 32 + quad * 8];
            short8 xb  = *(const short8*)&xs[(1 * 16 + col) * 264 + kk * 32 + quad * 8];
            __builtin_amdgcn_sched_barrier(0);  // loads may NOT sink past here
            // --- consume: 8 MFMAs ---
            acc[0][0] = __builtin_amdgcn_mfma_f32_16x16x32_bf16(wf0, xa, acc[0][0], 0, 0, 0);
            acc[1][0] = __builtin_amdgcn_mfma_f32_16x16x32_bf16(wf0, xb, acc[1][0], 0, 0, 0);
            acc[0][1] = __builtin_amdgcn_mfma_f32_16x16x32_bf16(wf1, xa, acc[0][1], 0, 0, 0);
            acc[1][1] = __builtin_amdgcn_mfma_f32_16x16x32_bf16(wf1, xb, acc[1][1], 0, 0, 0);
            acc[0][2] = __builtin_amdgcn_mfma_f32_16x16x32_bf16(wf2, xa, acc[0][2], 0, 0, 0);
            acc[1][2] = __builtin_amdgcn_mfma_f32_16x16x32_bf16(wf2, xb, acc[1][2], 0, 0, 0);
            acc[0][3] = __builtin_amdgcn_mfma_f32_16x16x32_bf16(wf3, xa, acc[0][3], 0, 0, 0);
            acc[1][3] = __builtin_amdgcn_mfma_f32_16x16x32_bf16(wf3, xb, acc[1][3], 0, 0, 0);
        }

        if (y == 0) {
            #pragma unroll
            for (int nt = 0; nt < 4; nt++) {
                int ch = wave * 64 + nt * 16 + quad * 4;
                float4 bi = *(const float4*)&bqkvs[ch];
                int h = ch >> 5, d = ch & 31;
                #pragma unroll
                for (int mt = 0; mt < 2; mt++) {
                    int n = n0 + mt * 16 + col;
                    short4v s = { f2bf(acc[mt][nt][0] + bi.x), f2bf(acc[mt][nt][1] + bi.y),
                                  f2bf(acc[mt][nt][2] + bi.z), f2bf(acc[mt][nt][3] + bi.w) };
                    *(short4v*)(qbf + ((size_t)(b * 8 + h) * 2048 + n) * 32 + d) = s;
                }
            }
        } else if (y == 1) {
            #pragma unroll
            for (int nt = 0; nt < 4; nt++) {
                int ch = wave * 64 + nt * 16 + quad * 4;
                float4 bi = *(const float4*)&bqkvs[256 + ch];
                int h = ch >> 5, d = ch & 31;
                #pragma unroll
                for (int mt = 0; mt < 2; mt++) {
                    int n = n0 + mt * 16 + col;
                    short4v s = { f2bf(acc[mt][nt][0] + bi.x), f2bf(acc[mt][nt][1] + bi.y),
                                  f2bf(acc[mt][nt][2] + bi.z), f2bf(acc[mt][nt][3] + bi.w) };
                    // fragment-major K tile store
                    int f  = ((n & 63) >> 5) * 2 + (d >> 4);
                    int lk = (n & 31) + (((d >> 3) & 1) << 5);
                    short* dst = kbf + ((size_t)(b * 8 + h) * 32 + (n >> 6)) * 2048
                               + f * 512 + lk * 8 + (d & 7);
                    *(short4v*)dst = s;
                }
            }
        } else {
            __syncthreads();                    // MFMA loop done -> xs dead
            #pragma unroll
            for (int nt = 0; nt < 4; nt++) {
                int ch = wave * 64 + nt * 16 + quad * 4;
                float4 bi = *(const float4*)&bqkvs[512 + ch];
                #pragma unroll
                for (int mt = 0; mt < 2; mt++) {
                    int tok = mt * 16 + col;
                    vtmp[(ch + 0) * 34 + tok] = f2bf(acc[mt][nt][0] + bi.x);
                    vtmp[(ch + 1) * 34 + tok] = f2bf(acc[mt][nt][1] + bi.y);
                    vtmp[(ch + 2) * 34 + tok] = f2bf(acc[mt][nt][2] + bi.z);
                    vtmp[(ch + 3) * 34 + tok] = f2bf(acc[mt][nt][3] + bi.w);
                }
            }
            __syncthreads();
            {
                int ch = tid;
                short s[32];
                #pragma unroll
                for (int t = 0; t < 32; t++) s[t] = vtmp[ch * 34 + t];
                int h = ch >> 5, d = ch & 31;
                size_t tile = (size_t)(b * 8 + h) * 32 + (n0 >> 6);
                short* dst = vtb + tile * 8192;
                #pragma unroll
                for (int g = 0; g < 4; g++) {
                    int kbse = (n0 & 63) + g * 8;   // key-base within 64-key tile
                    int f = kbse >> 4;              // kstep (dt = 0)
                    int h2 = (kbse >> 3) & 1;
                    *(short8*)(dst + f * 512 + (d + h2 * 32) * 8) = *(short8*)&s[g * 8];
                }
            }
        }
    }
}

// softmax+PV for one 16-key kstep (SX, S are literal constants; `cur`, `g`,
// `lane`, `lrun`, `o`, `u` from enclosing scope). Kept as a macro so all
// ext_vector indices stay compile-time constants (rule: runtime-indexed
// ext_vector arrays go to scratch).
#define ATTN_SMPV(A, SX, S)                                                     \
    do {                                                                        \
        float e0 = ex2(A[8*SX+0]), e1 = ex2(A[8*SX+1]);                         \
        float e2 = ex2(A[8*SX+2]), e3 = ex2(A[8*SX+3]);                         \
        float e4 = ex2(A[8*SX+4]), e5 = ex2(A[8*SX+5]);                         \
        float e6 = ex2(A[8*SX+6]), e7 = ex2(A[8*SX+7]);                         \
        lrun += ((e0 + e1) + (e2 + e3)) + ((e4 + e5) + (e6 + e7));              \
        uint32_t x0 = pkbf16(e0, e1), y0 = pkbf16(e4, e5);                      \
        uint32_t x1 = pkbf16(e2, e3), y1 = pkbf16(e6, e7);                      \
        asm("v_permlane32_swap_b32 %0, %1" : "+v"(x0), "+v"(y0));               \
        asm("v_permlane32_swap_b32 %0, %1" : "+v"(x1), "+v"(y1));               \
        u32x4 pv = { x0, x1, y0, y1 };                                          \
        short8 pf = __builtin_bit_cast(short8, pv);                             \
        __builtin_amdgcn_s_setprio(1);                                          \
        {                                                                       \
            short8 vf0 = *(const short8*)&u.Vs[g][cur][(0 * 4 + S) * 512 + lane * 8]; \
            o[0] = __builtin_amdgcn_mfma_f32_32x32x16_bf16(vf0, pf, o[0], 0, 0, 0);   \
            short8 vf1 = *(const short8*)&u.Vs[g][cur][(1 * 4 + S) * 512 + lane * 8]; \
            o[1] = __builtin_amdgcn_mfma_f32_32x32x16_bf16(vf1, pf, o[1], 0, 0, 0);   \
            short8 vf2 = *(const short8*)&u.Vs[g][cur][(2 * 4 + S) * 512 + lane * 8]; \
            o[2] = __builtin_amdgcn_mfma_f32_32x32x16_bf16(vf2, pf, o[2], 0, 0, 0);   \
            short8 vf3 = *(const short8*)&u.Vs[g][cur][(3 * 4 + S) * 512 + lane * 8]; \
            o[3] = __builtin_amdgcn_mfma_f32_32x32x16_bf16(vf3, pf, o[3], 0, 0, 0);   \
        }                                                                       \
        __builtin_amdgcn_s_setprio(0);                                          \
    } while (0)

// ---------------------------------------------------------------------------
// Kernel 3: MFMA flash attention, kt-split 8-wave blocks, 64 KB LDS.
// Round-12: in-place kf rotation — each kf pair is reloaded FOR TILE t+1
// immediately after its last QK^T use, so K's L2 latency hides under the
// following softmax+PV phase instead of being exposed at iter start (all 8
// waves used to stall together post-barrier). Named kf0..kf3 scalars + dead
// old values = no added live state; __launch_bounds__(512,4) pins the
// 128-unified-reg budget (= current 64 VGPR + 64 AGPR) so the allocator
// cannot rename past it (round-9 lesson: +16 regs halved residency).
// ---------------------------------------------------------------------------
__global__ __launch_bounds__(512, 4) void attn_kernel(
    const short* __restrict__ qb, const short* __restrict__ kb,
    const short* __restrict__ vtb,
    short* __restrict__ xob, short* __restrict__ ovb)
{
    __shared__ __align__(16) union {
        short Vs[2][2][8192];                               // 64 KB
        struct { float om[4][8][64][4]; float lm[256]; } m; // 33 KB
    } u;
    const int tid = threadIdx.x;
    const int wave = tid >> 6, lane = tid & 63;
    const int g = wave >> 2;                    // kt-half group
    const int lwave = wave & 3, lt = tid & 255;
    const int q32 = lane & 31, hi = lane >> 5;

    // XCD swizzle: dispatch D -> xcd = D%8; each XCD owns 4 whole heads.
    const int D = blockIdx.x;
    const int slot = D >> 3;
    const int bh = (D & 7) + ((slot & 3) << 3);
    const int qt = slot >> 2;
    const int m0 = qt * 128 + lwave * 32;
    const int b = bh >> 3, h = bh & 7;

    const short* qbase = qb + (size_t)bh * NSEQ * HD;
    const short* ksrc  = kb + (size_t)bh * 32 * 2048;    // 32 tiles x 4KB
    const short* vsrc  = vtb + (size_t)bh * 32 * 8192;   // 32 tiles x 16KB

    short8 qfrag[2];
    #pragma unroll
    for (int ks = 0; ks < 2; ks++)
        qfrag[ks] = *(const short8*)(qbase + (size_t)(m0 + q32) * 32 + ks * 16 + hi * 8);

    f32x16 o[4];
    #pragma unroll
    for (int dt = 0; dt < 4; dt++) o[dt] = zero16();
    float lrun = 0.f;

    auto STAGEV = [&](int buf, int t) {
        const short* vp = vsrc + (size_t)t * 8192 + lt * 8;
        #pragma unroll
        for (int p = 0; p < 4; p++)
            gload16(vp + p * 2048, &u.Vs[g][buf][p * 2048 + (lt >> 6) * 512]);
    };

    // prologue: K fragments for the first tile + V staging
    short8 kf0 = *(const short8*)(ksrc + (size_t)(g * 16) * 2048 + 0 * 512 + lane * 8);
    short8 kf1 = *(const short8*)(ksrc + (size_t)(g * 16) * 2048 + 1 * 512 + lane * 8);
    short8 kf2 = *(const short8*)(ksrc + (size_t)(g * 16) * 2048 + 2 * 512 + lane * 8);
    short8 kf3 = *(const short8*)(ksrc + (size_t)(g * 16) * 2048 + 3 * 512 + lane * 8);
    STAGEV(0, g * 16);
    __syncthreads();

    for (int t = 0; t < 16; t++) {
        const int cur = t & 1;
        const int kt = g * 16 + t;

        if (t < 15) STAGEV(cur ^ 1, kt + 1);    // V prefetch under compute

        // ---- 32-key tile tt=0 ----
        {
            f32x16 a = zero16();
            __builtin_amdgcn_s_setprio(1);
            a = __builtin_amdgcn_mfma_f32_32x32x16_bf16(kf0, qfrag[0], a, 0, 0, 0);
            a = __builtin_amdgcn_mfma_f32_32x32x16_bf16(kf1, qfrag[1], a, 0, 0, 0);
            __builtin_amdgcn_s_setprio(0);
            if (t < 15) {                       // kf0/kf1 dead: rotate in t+1's
                kf0 = *(const short8*)(ksrc + (size_t)(kt + 1) * 2048 + 0 * 512 + lane * 8);
                kf1 = *(const short8*)(ksrc + (size_t)(kt + 1) * 2048 + 1 * 512 + lane * 8);
            }
            ATTN_SMPV(a, 0, 0);
            ATTN_SMPV(a, 1, 1);
        }
        // ---- 32-key tile tt=1 ----
        {
            f32x16 a = zero16();
            __builtin_amdgcn_s_setprio(1);
            a = __builtin_amdgcn_mfma_f32_32x32x16_bf16(kf2, qfrag[0], a, 0, 0, 0);
            a = __builtin_amdgcn_mfma_f32_32x32x16_bf16(kf3, qfrag[1], a, 0, 0, 0);
            __builtin_amdgcn_s_setprio(0);
            if (t < 15) {                       // kf2/kf3 dead: rotate in t+1's
                kf2 = *(const short8*)(ksrc + (size_t)(kt + 1) * 2048 + 2 * 512 + lane * 8);
                kf3 = *(const short8*)(ksrc + (size_t)(kt + 1) * 2048 + 3 * 512 + lane * 8);
            }
            ATTN_SMPV(a, 0, 2);
            ATTN_SMPV(a, 1, 3);
        }
        __syncthreads();                        // drains prefetch, guards buf reuse
    }

    // ----- exact partial merge (no-max softmax => plain sums), two phases -----
    float lpart = lrun + __shfl_xor(lrun, 32);  // per-q partial l, all lanes
    float linv = 0.f;
    size_t mg = (size_t)b * 2048 + m0 + q32;

    // phase 1: dt 0..1
    if (g == 1) {
        #pragma unroll
        for (int dt = 0; dt < 2; dt++)
            #pragma unroll
            for (int q4 = 0; q4 < 4; q4++) {
                f32x4 c = { o[dt][q4*4+0], o[dt][q4*4+1], o[dt][q4*4+2], o[dt][q4*4+3] };
                *(f32x4*)&u.m.om[lwave][dt * 4 + q4][lane][0] = c;
            }
        u.m.lm[lwave * 64 + lane] = lpart;
    }
    __syncthreads();
    if (g == 0) {
        #pragma unroll
        for (int dt = 0; dt < 2; dt++)
            #pragma unroll
            for (int q4 = 0; q4 < 4; q4++) {
                f32x4 c = *(const f32x4*)&u.m.om[lwave][dt * 4 + q4][lane][0];
                o[dt][q4*4+0] += c[0]; o[dt][q4*4+1] += c[1];
                o[dt][q4*4+2] += c[2]; o[dt][q4*4+3] += c[3];
            }
        float l = lpart + u.m.lm[lwave * 64 + lane];
        linv = 1.0f / l;

        short* xr = xob + mg * 256 + h * 32;
        #pragma unroll
        for (int gg = 0; gg < 4; gg++) {        // dt=0: scalar out
            short4v sv = { f2bf(o[0][4*gg+0] * linv), f2bf(o[0][4*gg+1] * linv),
                           f2bf(o[0][4*gg+2] * linv), f2bf(o[0][4*gg+3] * linv) };
            *(short4v*)(xr + gg * 8 + hi * 4) = sv;
        }
        short* vr = ovb + mg * 768 + h * 32;
        #pragma unroll
        for (int gg = 0; gg < 4; gg++) {        // dt=1: vec row 0
            short4v sv = { f2bf(o[1][4*gg+0] * linv), f2bf(o[1][4*gg+1] * linv),
                           f2bf(o[1][4*gg+2] * linv), f2bf(o[1][4*gg+3] * linv) };
            *(short4v*)(vr + gg * 8 + hi * 4) = sv;
        }
    }
    __syncthreads();
    // phase 2: dt 2..3
    if (g == 1) {
        #pragma unroll
        for (int dt = 2; dt < 4; dt++)
            #pragma unroll
            for (int q4 = 0; q4 < 4; q4++) {
                f32x4 c = { o[dt][q4*4+0], o[dt][q4*4+1], o[dt][q4*4+2], o[dt][q4*4+3] };
                *(f32x4*)&u.m.om[lwave][(dt - 2) * 4 + q4][lane][0] = c;
            }
    }
    __syncthreads();
    if (g == 0) {
        short* vr = ovb + mg * 768 + h * 32;
        #pragma unroll
        for (int dt = 2; dt < 4; dt++) {
            #pragma unroll
            for (int q4 = 0; q4 < 4; q4++) {
                f32x4 c = *(const f32x4*)&u.m.om[lwave][(dt - 2) * 4 + q4][lane][0];
                o[dt][q4*4+0] += c[0]; o[dt][q4*4+1] += c[1];
                o[dt][q4*4+2] += c[2]; o[dt][q4*4+3] += c[3];
            }
            #pragma unroll
            for (int gg = 0; gg < 4; gg++) {
                short4v sv = { f2bf(o[dt][4*gg+0] * linv), f2bf(o[dt][4*gg+1] * linv),
                               f2bf(o[dt][4*gg+2] * linv), f2bf(o[dt][4*gg+3] * linv) };
                *(short4v*)(vr + (dt - 1) * 256 + gg * 8 + hi * 4) = sv;
            }
        }
    }
}

// ---------------------------------------------------------------------------
// Kernel 4: MFMA epilogue GEMM + fused combine. grid 512, block 512 (8 waves).
// ---------------------------------------------------------------------------
__global__ __launch_bounds__(512, 4) void ogemm_kernel(
    const float* __restrict__ x, const short* __restrict__ xob,
    const short* __restrict__ invb,
    const float* __restrict__ dotb, const float* __restrict__ normb,
    const short* __restrict__ ovb,
    const short* __restrict__ Wob, const short* __restrict__ Wgb,
    const float* __restrict__ bo, const float* __restrict__ bg,
    float* __restrict__ out)
{
    __shared__ __align__(16) union {
        struct { short inv[16 * 520]; short xo[16 * 264]; } in;
        struct { short gate[16 * 264]; short o[16 * 776]; } ob;
    } u;
    const int tid = threadIdx.x;
    const int M0 = blockIdx.x * 16;

    #pragma unroll
    for (int l = 0; l < 2; l++) {
        int i = l * 512 + tid;
        int m = i >> 6, seg = i & 63;
        *(short8*)&u.in.inv[m * 520 + seg * 8] =
            *(const short8*)(invb + (size_t)(M0 + m) * 512 + seg * 8);
    }
    {
        int m = tid >> 5, seg = tid & 31;
        *(short8*)&u.in.xo[m * 264 + seg * 8] =
            *(const short8*)(xob + (size_t)(M0 + m) * 256 + seg * 8);
    }
    __syncthreads();

    const int wave = tid >> 6, lane = tid & 63;
    const int col = lane & 15, quad = lane >> 4;
    const int cg = wave * 32;       // this wave's Wg channel base (2 tiles)
    const int co = wave * 96;       // this wave's Wo channel base (6 tiles)

    f32x4 accg[2], acco[6];
    #pragma unroll
    for (int i = 0; i < 2; i++) accg[i] = (f32x4){0.f,0.f,0.f,0.f};
    #pragma unroll
    for (int i = 0; i < 6; i++) acco[i] = (f32x4){0.f,0.f,0.f,0.f};

    #pragma unroll
    for (int kk = 0; kk < 8; kk++) {
        // --- issue all loads for this phase (10 global + 3 LDS) ---
        short8 wg0 = *(const short8*)(Wgb + (size_t)(cg + col) * 512 + (2*kk) * 32 + quad * 8);
        short8 wg1 = *(const short8*)(Wgb + (size_t)(cg + 16 + col) * 512 + (2*kk) * 32 + quad * 8);
        short8 wg2 = *(const short8*)(Wgb + (size_t)(cg + col) * 512 + (2*kk+1) * 32 + quad * 8);
        short8 wg3 = *(const short8*)(Wgb + (size_t)(cg + 16 + col) * 512 + (2*kk+1) * 32 + quad * 8);
        short8 wo0 = *(const short8*)(Wob + (size_t)(co + 0*16 + col) * 256 + kk * 32 + quad * 8);
        short8 wo1 = *(const short8*)(Wob + (size_t)(co + 1*16 + col) * 256 + kk * 32 + quad * 8);
        short8 wo2 = *(const short8*)(Wob + (size_t)(co + 2*16 + col) * 256 + kk * 32 + quad * 8);
        short8 wo3 = *(const short8*)(Wob + (size_t)(co + 3*16 + col) * 256 + kk * 32 + quad * 8);
        short8 wo4 = *(const short8*)(Wob + (size_t)(co + 4*16 + col) * 256 + kk * 32 + quad * 8);
        short8 wo5 = *(const short8*)(Wob + (size_t)(co + 5*16 + col) * 256 + kk * 32 + quad * 8);
        short8 xg0 = *(const short8*)&u.in.inv[col * 520 + (2*kk) * 32 + quad * 8];
        short8 xg1 = *(const short8*)&u.in.inv[col * 520 + (2*kk+1) * 32 + quad * 8];
        short8 xoo = *(const short8*)&u.in.xo[col * 264 + kk * 32 + quad * 8];
        __builtin_amdgcn_sched_barrier(0);      // loads may NOT sink past here
        // --- consume ---
        accg[0] = __builtin_amdgcn_mfma_f32_16x16x32_bf16(wg0, xg0, accg[0], 0, 0, 0);
        accg[1] = __builtin_amdgcn_mfma_f32_16x16x32_bf16(wg1, xg0, accg[1], 0, 0, 0);
        accg[0] = __builtin_amdgcn_mfma_f32_16x16x32_bf16(wg2, xg1, accg[0], 0, 0, 0);
        accg[1] = __builtin_amdgcn_mfma_f32_16x16x32_bf16(wg3, xg1, accg[1], 0, 0, 0);
        acco[0] = __builtin_amdgcn_mfma_f32_16x16x32_bf16(wo0, xoo, acco[0], 0, 0, 0);
        acco[1] = __builtin_amdgcn_mfma_f32_16x16x32_bf16(wo1, xoo, acco[1], 0, 0, 0);
        acco[2] = __builtin_amdgcn_mfma_f32_16x16x32_bf16(wo2, xoo, acco[2], 0, 0, 0);
        acco[3] = __builtin_amdgcn_mfma_f32_16x16x32_bf16(wo3, xoo, acco[3], 0, 0, 0);
        acco[4] = __builtin_amdgcn_mfma_f32_16x16x32_bf16(wo4, xoo, acco[4], 0, 0, 0);
        acco[5] = __builtin_amdgcn_mfma_f32_16x16x32_bf16(wo5, xoo, acco[5], 0, 0, 0);
    }
    __syncthreads();

    #pragma unroll
    for (int i = 0; i < 2; i++) {
        int ch = cg + i * 16 + quad * 4;
        float4 bi = *(const float4*)&bg[ch];
        short4v s = { f2bf(1.f / (1.f + __expf(-(accg[i][0] + bi.x)))),
                      f2bf(1.f / (1.f + __expf(-(accg[i][1] + bi.y)))),
                      f2bf(1.f / (1.f + __expf(-(accg[i][2] + bi.z)))),
                      f2bf(1.f / (1.f + __expf(-(accg[i][3] + bi.w)))) };
        *(short4v*)&u.ob.gate[col * 264 + ch] = s;
    }
    #pragma unroll
    for (int i = 0; i < 6; i++) {
        int ch = co + i * 16 + quad * 4;
        float4 bi = *(const float4*)&bo[ch];
        short4v s = { f2bf(acco[i][0] + bi.x), f2bf(acco[i][1] + bi.y),
                      f2bf(acco[i][2] + bi.z), f2bf(acco[i][3] + bi.w) };
        *(short4v*)&u.ob.o[col * 776 + ch] = s;
    }
    __syncthreads();

    #pragma unroll
    for (int l = 0; l < 8; l++) {
        int idx4 = l * 512 + tid;
        int m = idx4 >> 8;
        int j = (idx4 & 255) * 4;
        size_t mg = (size_t)(M0 + m);
        if (j < 256) {
            float4 dv = *(const float4*)(dotb + mg * 256 + j);
            float4 nv = *(const float4*)(normb + mg * 256 + j);
            short4v o1 = *(short4v*)&u.ob.o[m * 776 + j];
            short4v o2 = *(short4v*)&u.ob.o[m * 776 + 256 + j];
            short4v o3 = *(short4v*)&u.ob.o[m * 776 + 512 + j];
            float4 r;
            r.x = dv.x * bf2f(o1[0]) + nv.x * bf2f(o2[0]) + bf2f(o3[0]);
            r.y = dv.y * bf2f(o1[1]) + nv.y * bf2f(o2[1]) + bf2f(o3[1]);
            r.z = dv.z * bf2f(o1[2]) + nv.z * bf2f(o2[2]) + bf2f(o3[2]);
            r.w = dv.w * bf2f(o1[3]) + nv.w * bf2f(o2[3]) + bf2f(o3[3]);
            *(float4*)(out + mg * 1024 + j) = r;
        } else {
            int c = (j >> 8) - 1, jj = j & 255;
            short4v g4 = *(short4v*)&u.ob.gate[m * 264 + jj];
            short4v av4 = *(const short4v*)(ovb + mg * 768 + c * 256 + jj);
            float4 xv = *(const float4*)(x + mg * 1024 + 256 + c * 256 + jj);
            float4 r = { bf2f(g4[0]) * bf2f(av4[0]) + xv.x, bf2f(g4[1]) * bf2f(av4[1]) + xv.y,
                         bf2f(g4[2]) * bf2f(av4[2]) + xv.z, bf2f(g4[3]) * bf2f(av4[3]) + xv.w };
            *(float4*)(out + mg * 1024 + j) = r;
        }
    }
}

// ---------------------------------------------------------------------------
extern "C" void kernel_launch(void* const* d_in, const int* in_sizes, int n_in,
                              void* d_out, int out_size, void* d_ws, size_t ws_size,
                              hipStream_t stream)
{
    const float* x    = (const float*)d_in[0];
    const float* Wq   = (const float*)d_in[1];
    const float* bq   = (const float*)d_in[2];
    const float* Wk   = (const float*)d_in[3];
    const float* bk   = (const float*)d_in[4];
    const float* Wv   = (const float*)d_in[5];
    const float* bv   = (const float*)d_in[6];
    const float* Wvec = (const float*)d_in[7];
    const float* Wo   = (const float*)d_in[8];
    const float* bo   = (const float*)d_in[9];
    const float* Wg   = (const float*)d_in[10];
    const float* bg   = (const float*)d_in[11];
    const float* adp  = (const float*)d_in[12];
    const float* anp  = (const float*)d_in[13];
    float* out = (float*)d_out;

    float* ws    = (float*)d_ws;
    short* qbf   = (short*)ws;
    short* kbf   = (short*)(ws + 1048576);
    short* vtb   = (short*)(ws + 2097152);
    float* dotb  = ws + 6291456;
    float* normb = ws + 8388608;
    short* xob   = (short*)(ws + 10485760);
    short* ovb   = (short*)(ws + 11534336);
    short* invb  = (short*)(ws + 17825792);
    short* Wqkvb = (short*)(ws + 19922944);
    float* bqkvs = ws + 20021248;
    short* Wvecb = (short*)(ws + 20022016);
    short* Wob   = (short*)(ws + 20087552);
    short* Wgb   = (short*)(ws + 20185856);

    wcvt_kernel<<<2560, 256, 0, stream>>>(Wq, Wk, Wv, Wvec, Wo, Wg, bq, bk, bv,
                                          adp, anp, Wqkvb, Wvecb, Wob, Wgb, bqkvs);
    prep_kernel<<<1792, 256, 0, stream>>>(x, Wqkvb, bqkvs, Wvecb,
                                          qbf, kbf, vtb, dotb, invb, normb);
    attn_kernel<<<512, 512, 0, stream>>>(qbf, kbf, vtb, xob, ovb);
    ogemm_kernel<<<512, 512, 0, stream>>>(x, xob, invb, dotb, normb, ovb,
                                          Wob, Wgb, bo, bg, out);
}

// Round 14
// 238.486 us; speedup vs baseline: 1.0159x; 1.0159x over previous
//
#include <hip/hip_runtime.h>
#include <cstdint>
#include <cstddef>

#define HIDN 256
#define NHEAD 8
#define HD 32
#define NSEQ 2048
#define QS (0.17677669529663687f * 1.4426950408889634f)   // 1/sqrt(32) * log2(e)

typedef __attribute__((ext_vector_type(8))) short short8;
typedef __attribute__((ext_vector_type(4))) short short4v;
typedef __attribute__((ext_vector_type(4))) float f32x4;
typedef __attribute__((ext_vector_type(16))) float f32x16;
typedef __attribute__((ext_vector_type(4))) uint32_t u32x4;

static __device__ __forceinline__ short f2bf(float f) {
    union { float f; uint32_t u; } v; v.f = f;
    uint32_t r = (v.u + 0x7FFF + ((v.u >> 16) & 1)) >> 16;
    return (short)r;
}
static __device__ __forceinline__ float bf2f(short s) {
    union { uint32_t u; float f; } v; v.u = ((uint32_t)(uint16_t)s) << 16;
    return v.f;
}

// fast exp2: single v_exp_f32 (scores are small here)
static __device__ __forceinline__ float ex2(float x) {
#if defined(__has_builtin)
#if __has_builtin(__builtin_amdgcn_exp2f)
    return __builtin_amdgcn_exp2f(x);
#else
    return exp2f(x);
#endif
#else
    return exp2f(x);
#endif
}

// pack two f32 -> bf16x2 in one instruction (lo in [15:0], hi in [31:16])
static __device__ __forceinline__ uint32_t pkbf16(float lo, float hi) {
    uint32_t r;
    asm("v_cvt_pk_bf16_f32 %0, %1, %2" : "=v"(r) : "v"(lo), "v"(hi));
    return r;
}

// async global->LDS, 16B per lane; LDS dest = wave-uniform base + lane*16
static __device__ __forceinline__ void gload16(const void* g, void* l) {
    __builtin_amdgcn_global_load_lds(
        (__attribute__((address_space(1))) void*)g,
        (__attribute__((address_space(3))) void*)l, 16, 0, 0);
}

static __device__ __forceinline__ f32x16 zero16() {
    f32x16 z;
    #pragma unroll
    for (int i = 0; i < 16; i++) z[i] = 0.f;
    return z;
}

// ---------------------------------------------------------------------------
// Kernel 0: weight conversion (QS folded into Wq, alphas folded into Wg).
// ---------------------------------------------------------------------------
__global__ __launch_bounds__(256) void wcvt_kernel(
    const float* __restrict__ Wq, const float* __restrict__ Wk,
    const float* __restrict__ Wv, const float* __restrict__ Wvec,
    const float* __restrict__ Wo, const float* __restrict__ Wg,
    const float* __restrict__ bq, const float* __restrict__ bk,
    const float* __restrict__ bv,
    const float* __restrict__ ad, const float* __restrict__ an,
    short* __restrict__ Wqkvb, short* __restrict__ Wvecb,
    short* __restrict__ Wob, short* __restrict__ Wgb, float* __restrict__ bqkvs)
{
    int idx = blockIdx.x * 256 + threadIdx.x;
    if (idx < 65536)        Wqkvb[idx] = f2bf(Wq[idx] * QS);
    else if (idx < 131072)  Wqkvb[idx] = f2bf(Wk[idx - 65536]);
    else if (idx < 196608)  Wqkvb[idx] = f2bf(Wv[idx - 131072]);
    else if (idx < 327680)  Wvecb[idx - 196608] = f2bf(Wvec[idx - 196608]);
    else if (idx < 524288)  Wob[idx - 327680] = f2bf(Wo[idx - 327680]);
    else {
        int i2 = idx - 524288;
        int k = i2 & 511;
        float s = (k < 256) ? ad[0] : an[0];
        Wgb[i2] = f2bf(Wg[i2] * s);
    }
    if (idx < 256)          bqkvs[idx] = bq[idx] * QS;
    else if (idx < 512)     bqkvs[idx] = bk[idx - 256];
    else if (idx < 768)     bqkvs[idx] = bv[idx - 512];
}

// ---------------------------------------------------------------------------
// Kernel 1: FUSED prep = qkv + vec in one dispatch, 256-thr blocks.
// Round-11 load-batch + sched_barrier(0) pattern (confirmed: prep left the
// top-5). Blocks 0..1023: vec path. Blocks 1024..1791: qkv path.
//   kbf: [bh][kt(64keys)][frag f=t2*2+ks][lane][8 shorts]
//   vtb: [bh][kt][frag f=dt*4+ks][lane][8 shorts]
// ---------------------------------------------------------------------------
__global__ __launch_bounds__(256) void prep_kernel(
    const float* __restrict__ x, const short* __restrict__ Wqkvb,
    const float* __restrict__ bqkvs, const short* __restrict__ Wvecb,
    short* __restrict__ qbf, short* __restrict__ kbf, short* __restrict__ vtb,
    float* __restrict__ dotb, short* __restrict__ invb, float* __restrict__ normb)
{
    __shared__ __align__(16) short smem[3 * 16 * 264];   // 25.3 KB pool
    const int tid = threadIdx.x;
    const int D = blockIdx.x;

    const int wave = tid >> 6, lane = tid & 63;
    const int col = lane & 15, quad = lane >> 4;

    if (D < 1024) {
        // ================= vec path: 16 tokens x 128 channels =================
        const int half = D & 1;
        const int m0 = (D >> 1) * 16;
        const int b = m0 >> 11, n0 = m0 & 2047;

        #pragma unroll
        for (int p = 0; p < 12; p++) {
            int f4 = p * 256 + tid;
            int t = f4 / 192;
            int rem = f4 - t * 192;
            int c = rem >> 6, j4 = rem & 63;
            float4 v = *(const float4*)(x + (size_t)(m0 + t) * 1024 + 256 + c * 256 + j4 * 4);
            short4v s = { f2bf(v.x), f2bf(v.y), f2bf(v.z), f2bf(v.w) };
            *(short4v*)&smem[(c * 16 + t) * 264 + j4 * 4] = s;
        }
        __syncthreads();

        const int j0 = half * 128 + wave * 32;

        f32x4 d1[3][2], d2[3][2];
        #pragma unroll
        for (int c = 0; c < 3; c++)
            #pragma unroll
            for (int nt = 0; nt < 2; nt++) {
                d1[c][nt] = (f32x4){0.f,0.f,0.f,0.f};
                d2[c][nt] = (f32x4){0.f,0.f,0.f,0.f};
            }

        #pragma unroll
        for (int kk = 0; kk < 8; kk++) {
            // --- issue all loads for this phase (4 global + 3 LDS) ---
            short8 w1a = *(const short8*)&Wvecb[(size_t)(j0 + col) * 256 + kk * 32 + quad * 8];
            short8 w1b = *(const short8*)&Wvecb[(size_t)(j0 + 16 + col) * 256 + kk * 32 + quad * 8];
            short8 w2a = *(const short8*)&Wvecb[(size_t)(256 + j0 + col) * 256 + kk * 32 + quad * 8];
            short8 w2b = *(const short8*)&Wvecb[(size_t)(256 + j0 + 16 + col) * 256 + kk * 32 + quad * 8];
            short8 xf0 = *(const short8*)&smem[(0 * 16 + col) * 264 + kk * 32 + quad * 8];
            short8 xf1 = *(const short8*)&smem[(1 * 16 + col) * 264 + kk * 32 + quad * 8];
            short8 xf2 = *(const short8*)&smem[(2 * 16 + col) * 264 + kk * 32 + quad * 8];
            __builtin_amdgcn_sched_barrier(0);  // loads may NOT sink past here
            // --- consume: 12 MFMAs ---
            d1[0][0] = __builtin_amdgcn_mfma_f32_16x16x32_bf16(w1a, xf0, d1[0][0], 0, 0, 0);
            d1[0][1] = __builtin_amdgcn_mfma_f32_16x16x32_bf16(w1b, xf0, d1[0][1], 0, 0, 0);
            d2[0][0] = __builtin_amdgcn_mfma_f32_16x16x32_bf16(w2a, xf0, d2[0][0], 0, 0, 0);
            d2[0][1] = __builtin_amdgcn_mfma_f32_16x16x32_bf16(w2b, xf0, d2[0][1], 0, 0, 0);
            d1[1][0] = __builtin_amdgcn_mfma_f32_16x16x32_bf16(w1a, xf1, d1[1][0], 0, 0, 0);
            d1[1][1] = __builtin_amdgcn_mfma_f32_16x16x32_bf16(w1b, xf1, d1[1][1], 0, 0, 0);
            d2[1][0] = __builtin_amdgcn_mfma_f32_16x16x32_bf16(w2a, xf1, d2[1][0], 0, 0, 0);
            d2[1][1] = __builtin_amdgcn_mfma_f32_16x16x32_bf16(w2b, xf1, d2[1][1], 0, 0, 0);
            d1[2][0] = __builtin_amdgcn_mfma_f32_16x16x32_bf16(w1a, xf2, d1[2][0], 0, 0, 0);
            d1[2][1] = __builtin_amdgcn_mfma_f32_16x16x32_bf16(w1b, xf2, d1[2][1], 0, 0, 0);
            d2[2][0] = __builtin_amdgcn_mfma_f32_16x16x32_bf16(w2a, xf2, d2[2][0], 0, 0, 0);
            d2[2][1] = __builtin_amdgcn_mfma_f32_16x16x32_bf16(w2b, xf2, d2[2][1], 0, 0, 0);
        }
        #pragma unroll
        for (int nt = 0; nt < 2; nt++) {
            f32x4 dac = d1[0][nt] * d2[0][nt] + d1[1][nt] * d2[1][nt] + d1[2][nt] * d2[2][nt];
            float4 o = { dac[0], dac[1], dac[2], dac[3] };
            *(float4*)&dotb[(size_t)(m0 + col) * 256 + j0 + nt * 16 + quad * 4] = o;
            short4v s = { f2bf(dac[0]), f2bf(dac[1]), f2bf(dac[2]), f2bf(dac[3]) };
            *(short4v*)&invb[(size_t)(m0 + col) * 512 + j0 + nt * 16 + quad * 4] = s;
        }

        const int j = half * 128 + (tid & 127);
        const int tp = tid >> 7;                // 0..1
        #pragma unroll
        for (int t8 = 0; t8 < 8; t8++) {
            int t = tp * 8 + t8;
            float v0 = bf2f(smem[(0 * 16 + t) * 264 + j]);
            float v1 = bf2f(smem[(1 * 16 + t) * 264 + j]);
            float v2 = bf2f(smem[(2 * 16 + t) * 264 + j]);
            float nm = sqrtf(v0 * v0 + v1 * v1 + v2 * v2);
            normb[(size_t)(m0 + t) * 256 + j] = nm;
            invb[(size_t)(m0 + t) * 512 + 256 + j] = f2bf(nm);
        }
        {
            size_t tile = (size_t)(b * 8 + (j >> 5)) * 32 + (n0 >> 6);
            int kbse = (n0 & 63) + tp * 8;
            int ks = kbse >> 4, h2 = (kbse >> 3) & 1;
            #pragma unroll
            for (int c = 0; c < 3; c++) {
                short8 s;
                #pragma unroll
                for (int t8 = 0; t8 < 8; t8++) s[t8] = smem[(c * 16 + tp * 8 + t8) * 264 + j];
                int f = (1 + c) * 4 + ks;           // dt = 1+c
                *(short8*)(vtb + tile * 8192 + f * 512 + ((j & 31) + h2 * 32) * 8) = s;
            }
        }
    } else {
        // ================= qkv path =================
        short* xs   = smem;                     // 32*264 shorts (16.9 KB)
        short* vtmp = smem;                     // 256*34 shorts (17.4 KB) — alias
        const int E = D - 1024;
        const int y = E >> 8;                   // 0..2
        const int m0 = (E & 255) * 32;
        const int b  = m0 >> 11;
        const int n0 = m0 & 2047;

        #pragma unroll
        for (int l = 0; l < 8; l++) {
            int i = l * 256 + tid;
            int t = i >> 6, j4 = i & 63;
            float4 v = *(const float4*)(x + (size_t)(m0 + t) * 1024 + j4 * 4);
            short4v s = { f2bf(v.x), f2bf(v.y), f2bf(v.z), f2bf(v.w) };
            *(short4v*)&xs[t * 264 + j4 * 4] = s;
        }
        __syncthreads();

        f32x4 acc[2][4];
        #pragma unroll
        for (int mt = 0; mt < 2; mt++)
            #pragma unroll
            for (int nt = 0; nt < 4; nt++) acc[mt][nt] = (f32x4){0.f,0.f,0.f,0.f};

        const short* Wb = Wqkvb + (size_t)(y * 256 + wave * 64) * 256;
        #pragma unroll
        for (int kk = 0; kk < 8; kk++) {
            // --- issue all loads for this phase (4 global + 2 LDS) ---
            short8 wf0 = *(const short8*)(Wb + (size_t)(0 * 16 + col) * 256 + kk * 32 + quad * 8);
            short8 wf1 = *(const short8*)(Wb + (size_t)(1 * 16 + col) * 256 + kk * 32 + quad * 8);
            short8 wf2 = *(const short8*)(Wb + (size_t)(2 * 16 + col) * 256 + kk * 32 + quad * 8);
            short8 wf3 = *(const short8*)(Wb + (size_t)(3 * 16 + col) * 256 + kk * 32 + quad * 8);
            short8 xa  = *(const short8*)&xs[(0 * 16 + col) * 264 + kk * 32 + quad * 8];
            short8 xb  = *(const short8*)&xs[(1 * 16 + col) * 264 + kk * 32 + quad * 8];
            __builtin_amdgcn_sched_barrier(0);  // loads may NOT sink past here
            // --- consume: 8 MFMAs ---
            acc[0][0] = __builtin_amdgcn_mfma_f32_16x16x32_bf16(wf0, xa, acc[0][0], 0, 0, 0);
            acc[1][0] = __builtin_amdgcn_mfma_f32_16x16x32_bf16(wf0, xb, acc[1][0], 0, 0, 0);
            acc[0][1] = __builtin_amdgcn_mfma_f32_16x16x32_bf16(wf1, xa, acc[0][1], 0, 0, 0);
            acc[1][1] = __builtin_amdgcn_mfma_f32_16x16x32_bf16(wf1, xb, acc[1][1], 0, 0, 0);
            acc[0][2] = __builtin_amdgcn_mfma_f32_16x16x32_bf16(wf2, xa, acc[0][2], 0, 0, 0);
            acc[1][2] = __builtin_amdgcn_mfma_f32_16x16x32_bf16(wf2, xb, acc[1][2], 0, 0, 0);
            acc[0][3] = __builtin_amdgcn_mfma_f32_16x16x32_bf16(wf3, xa, acc[0][3], 0, 0, 0);
            acc[1][3] = __builtin_amdgcn_mfma_f32_16x16x32_bf16(wf3, xb, acc[1][3], 0, 0, 0);
        }

        if (y == 0) {
            #pragma unroll
            for (int nt = 0; nt < 4; nt++) {
                int ch = wave * 64 + nt * 16 + quad * 4;
                float4 bi = *(const float4*)&bqkvs[ch];
                int h = ch >> 5, d = ch & 31;
                #pragma unroll
                for (int mt = 0; mt < 2; mt++) {
                    int n = n0 + mt * 16 + col;
                    short4v s = { f2bf(acc[mt][nt][0] + bi.x), f2bf(acc[mt][nt][1] + bi.y),
                                  f2bf(acc[mt][nt][2] + bi.z), f2bf(acc[mt][nt][3] + bi.w) };
                    *(short4v*)(qbf + ((size_t)(b * 8 + h) * 2048 + n) * 32 + d) = s;
                }
            }
        } else if (y == 1) {
            #pragma unroll
            for (int nt = 0; nt < 4; nt++) {
                int ch = wave * 64 + nt * 16 + quad * 4;
                float4 bi = *(const float4*)&bqkvs[256 + ch];
                int h = ch >> 5, d = ch & 31;
                #pragma unroll
                for (int mt = 0; mt < 2; mt++) {
                    int n = n0 + mt * 16 + col;
                    short4v s = { f2bf(acc[mt][nt][0] + bi.x), f2bf(acc[mt][nt][1] + bi.y),
                                  f2bf(acc[mt][nt][2] + bi.z), f2bf(acc[mt][nt][3] + bi.w) };
                    // fragment-major K tile store
                    int f  = ((n & 63) >> 5) * 2 + (d >> 4);
                    int lk = (n & 31) + (((d >> 3) & 1) << 5);
                    short* dst = kbf + ((size_t)(b * 8 + h) * 32 + (n >> 6)) * 2048
                               + f * 512 + lk * 8 + (d & 7);
                    *(short4v*)dst = s;
                }
            }
        } else {
            __syncthreads();                    // MFMA loop done -> xs dead
            #pragma unroll
            for (int nt = 0; nt < 4; nt++) {
                int ch = wave * 64 + nt * 16 + quad * 4;
                float4 bi = *(const float4*)&bqkvs[512 + ch];
                #pragma unroll
                for (int mt = 0; mt < 2; mt++) {
                    int tok = mt * 16 + col;
                    vtmp[(ch + 0) * 34 + tok] = f2bf(acc[mt][nt][0] + bi.x);
                    vtmp[(ch + 1) * 34 + tok] = f2bf(acc[mt][nt][1] + bi.y);
                    vtmp[(ch + 2) * 34 + tok] = f2bf(acc[mt][nt][2] + bi.z);
                    vtmp[(ch + 3) * 34 + tok] = f2bf(acc[mt][nt][3] + bi.w);
                }
            }
            __syncthreads();
            {
                int ch = tid;
                short s[32];
                #pragma unroll
                for (int t = 0; t < 32; t++) s[t] = vtmp[ch * 34 + t];
                int h = ch >> 5, d = ch & 31;
                size_t tile = (size_t)(b * 8 + h) * 32 + (n0 >> 6);
                short* dst = vtb + tile * 8192;
                #pragma unroll
                for (int g = 0; g < 4; g++) {
                    int kbse = (n0 & 63) + g * 8;   // key-base within 64-key tile
                    int f = kbse >> 4;              // kstep (dt = 0)
                    int h2 = (kbse >> 3) & 1;
                    *(short8*)(dst + f * 512 + (d + h2 * 32) * 8) = *(short8*)&s[g * 8];
                }
            }
        }
    }
}

// ---------------------------------------------------------------------------
// Kernel 3: MFMA flash attention, kt-split 8-wave blocks, 64 KB LDS.
// Round-13: REVERTED to the round-11 configuration (best verified: 56.0 us,
// VGPR 64, no spill traffic). Round-12's kf rotation + launch_bounds(512,4)
// caused scratch spills (WRITE_SIZE 16384->20480 KB) and regressed to 57.5.
// Per-iter K loads (latency hidden by TLP — twice-verified), s_setprio
// around MFMA clusters (round-10 win). <=128 unified regs/wave is the
// residency budget: DO NOT add live state, do NOT pin launch bounds.
// ---------------------------------------------------------------------------
__global__ __launch_bounds__(512) void attn_kernel(
    const short* __restrict__ qb, const short* __restrict__ kb,
    const short* __restrict__ vtb,
    short* __restrict__ xob, short* __restrict__ ovb)
{
    __shared__ __align__(16) union {
        short Vs[2][2][8192];                               // 64 KB
        struct { float om[4][8][64][4]; float lm[256]; } m; // 33 KB
    } u;
    const int tid = threadIdx.x;
    const int wave = tid >> 6, lane = tid & 63;
    const int g = wave >> 2;                    // kt-half group
    const int lwave = wave & 3, lt = tid & 255;
    const int q32 = lane & 31, hi = lane >> 5;

    // XCD swizzle: dispatch D -> xcd = D%8; each XCD owns 4 whole heads.
    const int D = blockIdx.x;
    const int slot = D >> 3;
    const int bh = (D & 7) + ((slot & 3) << 3);
    const int qt = slot >> 2;
    const int m0 = qt * 128 + lwave * 32;
    const int b = bh >> 3, h = bh & 7;

    const short* qbase = qb + (size_t)bh * NSEQ * HD;
    const short* ksrc  = kb + (size_t)bh * 32 * 2048;    // 32 tiles x 4KB
    const short* vsrc  = vtb + (size_t)bh * 32 * 8192;   // 32 tiles x 16KB

    short8 qfrag[2];
    #pragma unroll
    for (int ks = 0; ks < 2; ks++)
        qfrag[ks] = *(const short8*)(qbase + (size_t)(m0 + q32) * 32 + ks * 16 + hi * 8);

    f32x16 o[4];
    #pragma unroll
    for (int dt = 0; dt < 4; dt++) o[dt] = zero16();
    float lrun = 0.f;

    auto STAGEV = [&](int buf, int t) {
        const short* vp = vsrc + (size_t)t * 8192 + lt * 8;
        #pragma unroll
        for (int p = 0; p < 4; p++)
            gload16(vp + p * 2048, &u.Vs[g][buf][p * 2048 + (lt >> 6) * 512]);
    };

    STAGEV(0, g * 16);
    __syncthreads();

    for (int t = 0; t < 16; t++) {
        const int cur = t & 1;
        const int kt = g * 16 + t;

        // K fragments: global -> registers (issued before V prefetch so the
        // QK^T waitcnt leaves the gload_lds queue untouched)
        short8 kf[4];
        #pragma unroll
        for (int f = 0; f < 4; f++)
            kf[f] = *(const short8*)(ksrc + (size_t)kt * 2048 + f * 512 + lane * 8);

        if (t < 15) STAGEV(cur ^ 1, kt + 1);    // prefetch under compute

        #pragma unroll
        for (int tt = 0; tt < 2; tt++) {
            // QK^T for this 32-key tile
            f32x16 a = zero16();
            __builtin_amdgcn_s_setprio(1);
            a = __builtin_amdgcn_mfma_f32_32x32x16_bf16(kf[2*tt+0], qfrag[0], a, 0, 0, 0);
            a = __builtin_amdgcn_mfma_f32_32x32x16_bf16(kf[2*tt+1], qfrag[1], a, 0, 0, 0);
            __builtin_amdgcn_s_setprio(0);

            // rolling: per 16-key kstep, exp2 -> pack -> pair-swap -> 4 PV MFMAs
            #pragma unroll
            for (int sx = 0; sx < 2; sx++) {
                float e0 = ex2(a[8*sx+0]), e1 = ex2(a[8*sx+1]);
                float e2 = ex2(a[8*sx+2]), e3 = ex2(a[8*sx+3]);
                float e4 = ex2(a[8*sx+4]), e5 = ex2(a[8*sx+5]);
                float e6 = ex2(a[8*sx+6]), e7 = ex2(a[8*sx+7]);
                lrun += ((e0 + e1) + (e2 + e3)) + ((e4 + e5) + (e6 + e7));
                uint32_t x0 = pkbf16(e0, e1), y0 = pkbf16(e4, e5);
                uint32_t x1 = pkbf16(e2, e3), y1 = pkbf16(e6, e7);
                asm("v_permlane32_swap_b32 %0, %1" : "+v"(x0), "+v"(y0));
                asm("v_permlane32_swap_b32 %0, %1" : "+v"(x1), "+v"(y1));
                u32x4 pv = { x0, x1, y0, y1 };
                short8 pf = __builtin_bit_cast(short8, pv);
                const int s = tt * 2 + sx;
                __builtin_amdgcn_s_setprio(1);
                #pragma unroll
                for (int dt = 0; dt < 4; dt++) {
                    short8 vf = *(const short8*)&u.Vs[g][cur][(dt * 4 + s) * 512 + lane * 8];
                    o[dt] = __builtin_amdgcn_mfma_f32_32x32x16_bf16(vf, pf, o[dt], 0, 0, 0);
                }
                __builtin_amdgcn_s_setprio(0);
            }
        }
        __syncthreads();                        // drains prefetch, guards buf reuse
    }

    // ----- exact partial merge (no-max softmax => plain sums), two phases -----
    float lpart = lrun + __shfl_xor(lrun, 32);  // per-q partial l, all lanes
    float linv = 0.f;
    size_t mg = (size_t)b * 2048 + m0 + q32;

    // phase 1: dt 0..1
    if (g == 1) {
        #pragma unroll
        for (int dt = 0; dt < 2; dt++)
            #pragma unroll
            for (int q4 = 0; q4 < 4; q4++) {
                f32x4 c = { o[dt][q4*4+0], o[dt][q4*4+1], o[dt][q4*4+2], o[dt][q4*4+3] };
                *(f32x4*)&u.m.om[lwave][dt * 4 + q4][lane][0] = c;
            }
        u.m.lm[lwave * 64 + lane] = lpart;
    }
    __syncthreads();
    if (g == 0) {
        #pragma unroll
        for (int dt = 0; dt < 2; dt++)
            #pragma unroll
            for (int q4 = 0; q4 < 4; q4++) {
                f32x4 c = *(const f32x4*)&u.m.om[lwave][dt * 4 + q4][lane][0];
                o[dt][q4*4+0] += c[0]; o[dt][q4*4+1] += c[1];
                o[dt][q4*4+2] += c[2]; o[dt][q4*4+3] += c[3];
            }
        float l = lpart + u.m.lm[lwave * 64 + lane];
        linv = 1.0f / l;

        short* xr = xob + mg * 256 + h * 32;
        #pragma unroll
        for (int gg = 0; gg < 4; gg++) {        // dt=0: scalar out
            short4v sv = { f2bf(o[0][4*gg+0] * linv), f2bf(o[0][4*gg+1] * linv),
                           f2bf(o[0][4*gg+2] * linv), f2bf(o[0][4*gg+3] * linv) };
            *(short4v*)(xr + gg * 8 + hi * 4) = sv;
        }
        short* vr = ovb + mg * 768 + h * 32;
        #pragma unroll
        for (int gg = 0; gg < 4; gg++) {        // dt=1: vec row 0
            short4v sv = { f2bf(o[1][4*gg+0] * linv), f2bf(o[1][4*gg+1] * linv),
                           f2bf(o[1][4*gg+2] * linv), f2bf(o[1][4*gg+3] * linv) };
            *(short4v*)(vr + gg * 8 + hi * 4) = sv;
        }
    }
    __syncthreads();
    // phase 2: dt 2..3
    if (g == 1) {
        #pragma unroll
        for (int dt = 2; dt < 4; dt++)
            #pragma unroll
            for (int q4 = 0; q4 < 4; q4++) {
                f32x4 c = { o[dt][q4*4+0], o[dt][q4*4+1], o[dt][q4*4+2], o[dt][q4*4+3] };
                *(f32x4*)&u.m.om[lwave][(dt - 2) * 4 + q4][lane][0] = c;
            }
    }
    __syncthreads();
    if (g == 0) {
        short* vr = ovb + mg * 768 + h * 32;
        #pragma unroll
        for (int dt = 2; dt < 4; dt++) {
            #pragma unroll
            for (int q4 = 0; q4 < 4; q4++) {
                f32x4 c = *(const f32x4*)&u.m.om[lwave][(dt - 2) * 4 + q4][lane][0];
                o[dt][q4*4+0] += c[0]; o[dt][q4*4+1] += c[1];
                o[dt][q4*4+2] += c[2]; o[dt][q4*4+3] += c[3];
            }
            #pragma unroll
            for (int gg = 0; gg < 4; gg++) {
                short4v sv = { f2bf(o[dt][4*gg+0] * linv), f2bf(o[dt][4*gg+1] * linv),
                               f2bf(o[dt][4*gg+2] * linv), f2bf(o[dt][4*gg+3] * linv) };
                *(short4v*)(vr + (dt - 1) * 256 + gg * 8 + hi * 4) = sv;
            }
        }
    }
}

// ---------------------------------------------------------------------------
// Kernel 4: MFMA epilogue GEMM + fused combine. grid 512, block 512 (8 waves).
// ---------------------------------------------------------------------------
__global__ __launch_bounds__(512, 4) void ogemm_kernel(
    const float* __restrict__ x, const short* __restrict__ xob,
    const short* __restrict__ invb,
    const float* __restrict__ dotb, const float* __restrict__ normb,
    const short* __restrict__ ovb,
    const short* __restrict__ Wob, const short* __restrict__ Wgb,
    const float* __restrict__ bo, const float* __restrict__ bg,
    float* __restrict__ out)
{
    __shared__ __align__(16) union {
        struct { short inv[16 * 520]; short xo[16 * 264]; } in;
        struct { short gate[16 * 264]; short o[16 * 776]; } ob;
    } u;
    const int tid = threadIdx.x;
    const int M0 = blockIdx.x * 16;

    #pragma unroll
    for (int l = 0; l < 2; l++) {
        int i = l * 512 + tid;
        int m = i >> 6, seg = i & 63;
        *(short8*)&u.in.inv[m * 520 + seg * 8] =
            *(const short8*)(invb + (size_t)(M0 + m) * 512 + seg * 8);
    }
    {
        int m = tid >> 5, seg = tid & 31;
        *(short8*)&u.in.xo[m * 264 + seg * 8] =
            *(const short8*)(xob + (size_t)(M0 + m) * 256 + seg * 8);
    }
    __syncthreads();

    const int wave = tid >> 6, lane = tid & 63;
    const int col = lane & 15, quad = lane >> 4;
    const int cg = wave * 32;       // this wave's Wg channel base (2 tiles)
    const int co = wave * 96;       // this wave's Wo channel base (6 tiles)

    f32x4 accg[2], acco[6];
    #pragma unroll
    for (int i = 0; i < 2; i++) accg[i] = (f32x4){0.f,0.f,0.f,0.f};
    #pragma unroll
    for (int i = 0; i < 6; i++) acco[i] = (f32x4){0.f,0.f,0.f,0.f};

    #pragma unroll
    for (int kk = 0; kk < 8; kk++) {
        // --- issue all loads for this phase (10 global + 3 LDS) ---
        short8 wg0 = *(const short8*)(Wgb + (size_t)(cg + col) * 512 + (2*kk) * 32 + quad * 8);
        short8 wg1 = *(const short8*)(Wgb + (size_t)(cg + 16 + col) * 512 + (2*kk) * 32 + quad * 8);
        short8 wg2 = *(const short8*)(Wgb + (size_t)(cg + col) * 512 + (2*kk+1) * 32 + quad * 8);
        short8 wg3 = *(const short8*)(Wgb + (size_t)(cg + 16 + col) * 512 + (2*kk+1) * 32 + quad * 8);
        short8 wo0 = *(const short8*)(Wob + (size_t)(co + 0*16 + col) * 256 + kk * 32 + quad * 8);
        short8 wo1 = *(const short8*)(Wob + (size_t)(co + 1*16 + col) * 256 + kk * 32 + quad * 8);
        short8 wo2 = *(const short8*)(Wob + (size_t)(co + 2*16 + col) * 256 + kk * 32 + quad * 8);
        short8 wo3 = *(const short8*)(Wob + (size_t)(co + 3*16 + col) * 256 + kk * 32 + quad * 8);
        short8 wo4 = *(const short8*)(Wob + (size_t)(co + 4*16 + col) * 256 + kk * 32 + quad * 8);
        short8 wo5 = *(const short8*)(Wob + (size_t)(co + 5*16 + col) * 256 + kk * 32 + quad * 8);
        short8 xg0 = *(const short8*)&u.in.inv[col * 520 + (2*kk) * 32 + quad * 8];
        short8 xg1 = *(const short8*)&u.in.inv[col * 520 + (2*kk+1) * 32 + quad * 8];
        short8 xoo = *(const short8*)&u.in.xo[col * 264 + kk * 32 + quad * 8];
        __builtin_amdgcn_sched_barrier(0);      // loads may NOT sink past here
        // --- consume ---
        accg[0] = __builtin_amdgcn_mfma_f32_16x16x32_bf16(wg0, xg0, accg[0], 0, 0, 0);
        accg[1] = __builtin_amdgcn_mfma_f32_16x16x32_bf16(wg1, xg0, accg[1], 0, 0, 0);
        accg[0] = __builtin_amdgcn_mfma_f32_16x16x32_bf16(wg2, xg1, accg[0], 0, 0, 0);
        accg[1] = __builtin_amdgcn_mfma_f32_16x16x32_bf16(wg3, xg1, accg[1], 0, 0, 0);
        acco[0] = __builtin_amdgcn_mfma_f32_16x16x32_bf16(wo0, xoo, acco[0], 0, 0, 0);
        acco[1] = __builtin_amdgcn_mfma_f32_16x16x32_bf16(wo1, xoo, acco[1], 0, 0, 0);
        acco[2] = __builtin_amdgcn_mfma_f32_16x16x32_bf16(wo2, xoo, acco[2], 0, 0, 0);
        acco[3] = __builtin_amdgcn_mfma_f32_16x16x32_bf16(wo3, xoo, acco[3], 0, 0, 0);
        acco[4] = __builtin_amdgcn_mfma_f32_16x16x32_bf16(wo4, xoo, acco[4], 0, 0, 0);
        acco[5] = __builtin_amdgcn_mfma_f32_16x16x32_bf16(wo5, xoo, acco[5], 0, 0, 0);
    }
    __syncthreads();

    #pragma unroll
    for (int i = 0; i < 2; i++) {
        int ch = cg + i * 16 + quad * 4;
        float4 bi = *(const float4*)&bg[ch];
        short4v s = { f2bf(1.f / (1.f + __expf(-(accg[i][0] + bi.x)))),
                      f2bf(1.f / (1.f + __expf(-(accg[i][1] + bi.y)))),
                      f2bf(1.f / (1.f + __expf(-(accg[i][2] + bi.z)))),
                      f2bf(1.f / (1.f + __expf(-(accg[i][3] + bi.w)))) };
        *(short4v*)&u.ob.gate[col * 264 + ch] = s;
    }
    #pragma unroll
    for (int i = 0; i < 6; i++) {
        int ch = co + i * 16 + quad * 4;
        float4 bi = *(const float4*)&bo[ch];
        short4v s = { f2bf(acco[i][0] + bi.x), f2bf(acco[i][1] + bi.y),
                      f2bf(acco[i][2] + bi.z), f2bf(acco[i][3] + bi.w) };
        *(short4v*)&u.ob.o[col * 776 + ch] = s;
    }
    __syncthreads();

    #pragma unroll
    for (int l = 0; l < 8; l++) {
        int idx4 = l * 512 + tid;
        int m = idx4 >> 8;
        int j = (idx4 & 255) * 4;
        size_t mg = (size_t)(M0 + m);
        if (j < 256) {
            float4 dv = *(const float4*)(dotb + mg * 256 + j);
            float4 nv = *(const float4*)(normb + mg * 256 + j);
            short4v o1 = *(short4v*)&u.ob.o[m * 776 + j];
            short4v o2 = *(short4v*)&u.ob.o[m * 776 + 256 + j];
            short4v o3 = *(short4v*)&u.ob.o[m * 776 + 512 + j];
            float4 r;
            r.x = dv.x * bf2f(o1[0]) + nv.x * bf2f(o2[0]) + bf2f(o3[0]);
            r.y = dv.y * bf2f(o1[1]) + nv.y * bf2f(o2[1]) + bf2f(o3[1]);
            r.z = dv.z * bf2f(o1[2]) + nv.z * bf2f(o2[2]) + bf2f(o3[2]);
            r.w = dv.w * bf2f(o1[3]) + nv.w * bf2f(o2[3]) + bf2f(o3[3]);
            *(float4*)(out + mg * 1024 + j) = r;
        } else {
            int c = (j >> 8) - 1, jj = j & 255;
            short4v g4 = *(short4v*)&u.ob.gate[m * 264 + jj];
            short4v av4 = *(const short4v*)(ovb + mg * 768 + c * 256 + jj);
            float4 xv = *(const float4*)(x + mg * 1024 + 256 + c * 256 + jj);
            float4 r = { bf2f(g4[0]) * bf2f(av4[0]) + xv.x, bf2f(g4[1]) * bf2f(av4[1]) + xv.y,
                         bf2f(g4[2]) * bf2f(av4[2]) + xv.z, bf2f(g4[3]) * bf2f(av4[3]) + xv.w };
            *(float4*)(out + mg * 1024 + j) = r;
        }
    }
}

// ---------------------------------------------------------------------------
extern "C" void kernel_launch(void* const* d_in, const int* in_sizes, int n_in,
                              void* d_out, int out_size, void* d_ws, size_t ws_size,
                              hipStream_t stream)
{
    const float* x    = (const float*)d_in[0];
    const float* Wq   = (const float*)d_in[1];
    const float* bq   = (const float*)d_in[2];
    const float* Wk   = (const float*)d_in[3];
    const float* bk   = (const float*)d_in[4];
    const float* Wv   = (const float*)d_in[5];
    const float* bv   = (const float*)d_in[6];
    const float* Wvec = (const float*)d_in[7];
    const float* Wo   = (const float*)d_in[8];
    const float* bo   = (const float*)d_in[9];
    const float* Wg   = (const float*)d_in[10];
    const float* bg   = (const float*)d_in[11];
    const float* adp  = (const float*)d_in[12];
    const float* anp  = (const float*)d_in[13];
    float* out = (float*)d_out;

    float* ws    = (float*)d_ws;
    short* qbf   = (short*)ws;
    short* kbf   = (short*)(ws + 1048576);
    short* vtb   = (short*)(ws + 2097152);
    float* dotb  = ws + 6291456;
    float* normb = ws + 8388608;
    short* xob   = (short*)(ws + 10485760);
    short* ovb   = (short*)(ws + 11534336);
    short* invb  = (short*)(ws + 17825792);
    short* Wqkvb = (short*)(ws + 19922944);
    float* bqkvs = ws + 20021248;
    short* Wvecb = (short*)(ws + 20022016);
    short* Wob   = (short*)(ws + 20087552);
    short* Wgb   = (short*)(ws + 20185856);

    wcvt_kernel<<<2560, 256, 0, stream>>>(Wq, Wk, Wv, Wvec, Wo, Wg, bq, bk, bv,
                                          adp, anp, Wqkvb, Wvecb, Wob, Wgb, bqkvs);
    prep_kernel<<<1792, 256, 0, stream>>>(x, Wqkvb, bqkvs, Wvecb,
                                          qbf, kbf, vtb, dotb, invb, normb);
    attn_kernel<<<512, 512, 0, stream>>>(qbf, kbf, vtb, xob, ovb);
    ogemm_kernel<<<512, 512, 0, stream>>>(x, xob, invb, dotb, normb, ovb,
                                          Wob, Wgb, bo, bg, out);
}

// Round 15
// 234.027 us; speedup vs baseline: 1.0352x; 1.0191x over previous
//
#include <hip/hip_runtime.h>
#include <cstdint>
#include <cstddef>

#define HIDN 256
#define NHEAD 8
#define HD 32
#define NSEQ 2048
#define QS (0.17677669529663687f * 1.4426950408889634f)   // 1/sqrt(32) * log2(e)

typedef __attribute__((ext_vector_type(8))) short short8;
typedef __attribute__((ext_vector_type(4))) short short4v;
typedef __attribute__((ext_vector_type(4))) float f32x4;
typedef __attribute__((ext_vector_type(16))) float f32x16;
typedef __attribute__((ext_vector_type(4))) uint32_t u32x4;

static __device__ __forceinline__ short f2bf(float f) {
    union { float f; uint32_t u; } v; v.f = f;
    uint32_t r = (v.u + 0x7FFF + ((v.u >> 16) & 1)) >> 16;
    return (short)r;
}
static __device__ __forceinline__ float bf2f(short s) {
    union { uint32_t u; float f; } v; v.u = ((uint32_t)(uint16_t)s) << 16;
    return v.f;
}

// fast exp2: single v_exp_f32 (scores are small here)
static __device__ __forceinline__ float ex2(float x) {
#if defined(__has_builtin)
#if __has_builtin(__builtin_amdgcn_exp2f)
    return __builtin_amdgcn_exp2f(x);
#else
    return exp2f(x);
#endif
#else
    return exp2f(x);
#endif
}

// pack two f32 -> bf16x2 in one instruction (lo in [15:0], hi in [31:16])
static __device__ __forceinline__ uint32_t pkbf16(float lo, float hi) {
    uint32_t r;
    asm("v_cvt_pk_bf16_f32 %0, %1, %2" : "=v"(r) : "v"(lo), "v"(hi));
    return r;
}

// async global->LDS, 16B per lane; LDS dest = wave-uniform base + lane*16
static __device__ __forceinline__ void gload16(const void* g, void* l) {
    __builtin_amdgcn_global_load_lds(
        (__attribute__((address_space(1))) void*)g,
        (__attribute__((address_space(3))) void*)l, 16, 0, 0);
}

static __device__ __forceinline__ f32x16 zero16() {
    f32x16 z;
    #pragma unroll
    for (int i = 0; i < 16; i++) z[i] = 0.f;
    return z;
}

// ---------------------------------------------------------------------------
// Kernel 0: weight conversion (QS folded into Wq, alphas folded into Wg).
// ---------------------------------------------------------------------------
__global__ __launch_bounds__(256) void wcvt_kernel(
    const float* __restrict__ Wq, const float* __restrict__ Wk,
    const float* __restrict__ Wv, const float* __restrict__ Wvec,
    const float* __restrict__ Wo, const float* __restrict__ Wg,
    const float* __restrict__ bq, const float* __restrict__ bk,
    const float* __restrict__ bv,
    const float* __restrict__ ad, const float* __restrict__ an,
    short* __restrict__ Wqkvb, short* __restrict__ Wvecb,
    short* __restrict__ Wob, short* __restrict__ Wgb, float* __restrict__ bqkvs)
{
    int idx = blockIdx.x * 256 + threadIdx.x;
    if (idx < 65536)        Wqkvb[idx] = f2bf(Wq[idx] * QS);
    else if (idx < 131072)  Wqkvb[idx] = f2bf(Wk[idx - 65536]);
    else if (idx < 196608)  Wqkvb[idx] = f2bf(Wv[idx - 131072]);
    else if (idx < 327680)  Wvecb[idx - 196608] = f2bf(Wvec[idx - 196608]);
    else if (idx < 524288)  Wob[idx - 327680] = f2bf(Wo[idx - 327680]);
    else {
        int i2 = idx - 524288;
        int k = i2 & 511;
        float s = (k < 256) ? ad[0] : an[0];
        Wgb[i2] = f2bf(Wg[i2] * s);
    }
    if (idx < 256)          bqkvs[idx] = bq[idx] * QS;
    else if (idx < 512)     bqkvs[idx] = bk[idx - 256];
    else if (idx < 768)     bqkvs[idx] = bv[idx - 512];
}

// ---------------------------------------------------------------------------
// Kernel 1: fused QKV via MFMA. Round-14: UN-FUSED back to the round-8
// configuration (session-best 234.9 us e2e): grid 768 — the y in {q,k,v}
// loop split across blocks, 3 blocks/CU, 12 waves/CU. The round-9 fusion
// into prep_kernel duplicated vec's x-staging per channel-half and ran vec
// at 4-wave blocks; it cost ~3-5 us and was never a win.
//   kbf: [bh][kt(64keys)][frag f=t2*2+ks][lane][8 shorts]
//   vtb: [bh][kt][frag f=dt*4+ks][lane][8 shorts]
// ---------------------------------------------------------------------------
__global__ __launch_bounds__(256) void qkv_kernel(
    const float* __restrict__ x, const short* __restrict__ Wqkvb,
    const float* __restrict__ bqkvs,
    short* __restrict__ qbf, short* __restrict__ kbf, short* __restrict__ vtb)
{
    __shared__ short xs[32 * 264];
    __shared__ short vtmp[256 * 34];
    const int tid = threadIdx.x;
    const int D = blockIdx.x;
    const int y = D >> 8;                       // 0..2
    const int m0 = (D & 255) * 32;
    const int b  = m0 >> 11;
    const int n0 = m0 & 2047;

    #pragma unroll
    for (int l = 0; l < 8; l++) {
        int i = l * 256 + tid;
        int t = i >> 6, j4 = i & 63;
        float4 v = *(const float4*)(x + (size_t)(m0 + t) * 1024 + j4 * 4);
        short4v s = { f2bf(v.x), f2bf(v.y), f2bf(v.z), f2bf(v.w) };
        *(short4v*)&xs[t * 264 + j4 * 4] = s;
    }
    __syncthreads();

    const int wave = tid >> 6, lane = tid & 63;
    const int col = lane & 15, quad = lane >> 4;

    short8 xf[2][8];
    #pragma unroll
    for (int mt = 0; mt < 2; mt++)
        #pragma unroll
        for (int kk = 0; kk < 8; kk++)
            xf[mt][kk] = *(const short8*)&xs[(mt * 16 + col) * 264 + kk * 32 + quad * 8];

    f32x4 acc[2][4];
    #pragma unroll
    for (int mt = 0; mt < 2; mt++)
        #pragma unroll
        for (int nt = 0; nt < 4; nt++) acc[mt][nt] = (f32x4){0.f,0.f,0.f,0.f};

    const short* Wb = Wqkvb + (size_t)(y * 256 + wave * 64) * 256;
    #pragma unroll
    for (int kk = 0; kk < 8; kk++) {
        #pragma unroll
        for (int nt = 0; nt < 4; nt++) {
            short8 wf = *(const short8*)(Wb + (size_t)(nt * 16 + col) * 256 + kk * 32 + quad * 8);
            #pragma unroll
            for (int mt = 0; mt < 2; mt++)
                acc[mt][nt] = __builtin_amdgcn_mfma_f32_16x16x32_bf16(wf, xf[mt][kk], acc[mt][nt], 0, 0, 0);
        }
    }

    if (y == 0) {
        #pragma unroll
        for (int nt = 0; nt < 4; nt++) {
            int ch = wave * 64 + nt * 16 + quad * 4;
            float4 bi = *(const float4*)&bqkvs[ch];
            int h = ch >> 5, d = ch & 31;
            #pragma unroll
            for (int mt = 0; mt < 2; mt++) {
                int n = n0 + mt * 16 + col;
                short4v s = { f2bf(acc[mt][nt][0] + bi.x), f2bf(acc[mt][nt][1] + bi.y),
                              f2bf(acc[mt][nt][2] + bi.z), f2bf(acc[mt][nt][3] + bi.w) };
                *(short4v*)(qbf + ((size_t)(b * 8 + h) * 2048 + n) * 32 + d) = s;
            }
        }
    } else if (y == 1) {
        #pragma unroll
        for (int nt = 0; nt < 4; nt++) {
            int ch = wave * 64 + nt * 16 + quad * 4;
            float4 bi = *(const float4*)&bqkvs[256 + ch];
            int h = ch >> 5, d = ch & 31;
            #pragma unroll
            for (int mt = 0; mt < 2; mt++) {
                int n = n0 + mt * 16 + col;
                short4v s = { f2bf(acc[mt][nt][0] + bi.x), f2bf(acc[mt][nt][1] + bi.y),
                              f2bf(acc[mt][nt][2] + bi.z), f2bf(acc[mt][nt][3] + bi.w) };
                // fragment-major K tile store
                int f  = ((n & 63) >> 5) * 2 + (d >> 4);
                int lk = (n & 31) + (((d >> 3) & 1) << 5);
                short* dst = kbf + ((size_t)(b * 8 + h) * 32 + (n >> 6)) * 2048
                           + f * 512 + lk * 8 + (d & 7);
                *(short4v*)dst = s;
            }
        }
    } else {
        #pragma unroll
        for (int nt = 0; nt < 4; nt++) {
            int ch = wave * 64 + nt * 16 + quad * 4;
            float4 bi = *(const float4*)&bqkvs[512 + ch];
            #pragma unroll
            for (int mt = 0; mt < 2; mt++) {
                int tok = mt * 16 + col;
                vtmp[(ch + 0) * 34 + tok] = f2bf(acc[mt][nt][0] + bi.x);
                vtmp[(ch + 1) * 34 + tok] = f2bf(acc[mt][nt][1] + bi.y);
                vtmp[(ch + 2) * 34 + tok] = f2bf(acc[mt][nt][2] + bi.z);
                vtmp[(ch + 3) * 34 + tok] = f2bf(acc[mt][nt][3] + bi.w);
            }
        }
        __syncthreads();
        {
            int ch = tid;
            short s[32];
            #pragma unroll
            for (int t = 0; t < 32; t++) s[t] = vtmp[ch * 34 + t];
            int h = ch >> 5, d = ch & 31;
            size_t tile = (size_t)(b * 8 + h) * 32 + (n0 >> 6);
            short* dst = vtb + tile * 8192;
            #pragma unroll
            for (int g = 0; g < 4; g++) {
                int kbse = (n0 & 63) + g * 8;       // key-base within 64-key tile
                int f = kbse >> 4;                  // kstep (dt = 0)
                int h2 = (kbse >> 3) & 1;
                *(short8*)(dst + f * 512 + (d + h2 * 32) * 8) = *(short8*)&s[g * 8];
            }
        }
    }
}

// ---------------------------------------------------------------------------
// Kernel 2: fused vec_dot (MFMA) + vec_norm + V^T vec-rows (fragment-major
// vtb frags dt=1..3). grid 512 x 512 (round-8 configuration).
// ---------------------------------------------------------------------------
__global__ __launch_bounds__(512) void vec_kernel(
    const float* __restrict__ x, const short* __restrict__ Wvecb,
    float* __restrict__ dotb, short* __restrict__ invb,
    float* __restrict__ normb, short* __restrict__ vtb)
{
    __shared__ short vb[3 * 16 * 264];
    const int tid = threadIdx.x;
    const int m0 = blockIdx.x * 16;
    const int b = m0 >> 11, n0 = m0 & 2047;

    #pragma unroll
    for (int p = 0; p < 6; p++) {
        int f4 = p * 512 + tid;
        int t = f4 / 192;
        int rem = f4 - t * 192;
        int c = rem >> 6, j4 = rem & 63;
        float4 v = *(const float4*)(x + (size_t)(m0 + t) * 1024 + 256 + c * 256 + j4 * 4);
        short4v s = { f2bf(v.x), f2bf(v.y), f2bf(v.z), f2bf(v.w) };
        *(short4v*)&vb[(c * 16 + t) * 264 + j4 * 4] = s;
    }
    __syncthreads();

    const int wave = tid >> 6, lane = tid & 63;
    const int col = lane & 15, quad = lane >> 4;
    const int j0 = wave * 32;

    f32x4 d1[3][2], d2[3][2];
    #pragma unroll
    for (int c = 0; c < 3; c++)
        #pragma unroll
        for (int nt = 0; nt < 2; nt++) {
            d1[c][nt] = (f32x4){0.f,0.f,0.f,0.f};
            d2[c][nt] = (f32x4){0.f,0.f,0.f,0.f};
        }

    #pragma unroll
    for (int kk = 0; kk < 8; kk++) {
        short8 w1[2], w2[2];
        #pragma unroll
        for (int nt = 0; nt < 2; nt++) {
            w1[nt] = *(const short8*)&Wvecb[(size_t)(j0 + nt * 16 + col) * 256 + kk * 32 + quad * 8];
            w2[nt] = *(const short8*)&Wvecb[(size_t)(256 + j0 + nt * 16 + col) * 256 + kk * 32 + quad * 8];
        }
        #pragma unroll
        for (int c = 0; c < 3; c++) {
            short8 xf = *(const short8*)&vb[(c * 16 + col) * 264 + kk * 32 + quad * 8];
            #pragma unroll
            for (int nt = 0; nt < 2; nt++) {
                d1[c][nt] = __builtin_amdgcn_mfma_f32_16x16x32_bf16(w1[nt], xf, d1[c][nt], 0, 0, 0);
                d2[c][nt] = __builtin_amdgcn_mfma_f32_16x16x32_bf16(w2[nt], xf, d2[c][nt], 0, 0, 0);
            }
        }
    }
    #pragma unroll
    for (int nt = 0; nt < 2; nt++) {
        f32x4 dac = d1[0][nt] * d2[0][nt] + d1[1][nt] * d2[1][nt] + d1[2][nt] * d2[2][nt];
        float4 o = { dac[0], dac[1], dac[2], dac[3] };
        *(float4*)&dotb[(size_t)(m0 + col) * 256 + j0 + nt * 16 + quad * 4] = o;
        short4v s = { f2bf(dac[0]), f2bf(dac[1]), f2bf(dac[2]), f2bf(dac[3]) };
        *(short4v*)&invb[(size_t)(m0 + col) * 512 + j0 + nt * 16 + quad * 4] = s;
    }

    const int j = tid & 255, tp = tid >> 8;
    const int h = j >> 5, d = j & 31;
    #pragma unroll
    for (int t8 = 0; t8 < 8; t8++) {
        int t = tp * 8 + t8;
        float v0 = bf2f(vb[(0 * 16 + t) * 264 + j]);
        float v1 = bf2f(vb[(1 * 16 + t) * 264 + j]);
        float v2 = bf2f(vb[(2 * 16 + t) * 264 + j]);
        float nm = sqrtf(v0 * v0 + v1 * v1 + v2 * v2);
        normb[(size_t)(m0 + t) * 256 + j] = nm;
        invb[(size_t)(m0 + t) * 512 + 256 + j] = f2bf(nm);
    }
    {
        size_t tile = (size_t)(b * 8 + h) * 32 + (n0 >> 6);
        int kbse = (n0 & 63) + tp * 8;
        int ks = kbse >> 4, h2 = (kbse >> 3) & 1;
        #pragma unroll
        for (int c = 0; c < 3; c++) {
            short8 s;
            #pragma unroll
            for (int t8 = 0; t8 < 8; t8++) s[t8] = vb[(c * 16 + tp * 8 + t8) * 264 + j];
            int f = (1 + c) * 4 + ks;               // dt = 1+c
            *(short8*)(vtb + tile * 8192 + f * 512 + (d + h2 * 32) * 8) = s;
        }
    }
}

// ---------------------------------------------------------------------------
// Kernel 3: MFMA flash attention, kt-split 8-wave blocks, 64 KB LDS.
// Round-11/13 configuration (best verified: 56.0 us, VGPR 64, no spills).
// Per-iter K loads (latency hidden by TLP — twice-verified), s_setprio
// around MFMA clusters. <=128 unified regs/wave is the residency budget:
// DO NOT add live state, do NOT pin launch bounds.
// ---------------------------------------------------------------------------
__global__ __launch_bounds__(512) void attn_kernel(
    const short* __restrict__ qb, const short* __restrict__ kb,
    const short* __restrict__ vtb,
    short* __restrict__ xob, short* __restrict__ ovb)
{
    __shared__ __align__(16) union {
        short Vs[2][2][8192];                               // 64 KB
        struct { float om[4][8][64][4]; float lm[256]; } m; // 33 KB
    } u;
    const int tid = threadIdx.x;
    const int wave = tid >> 6, lane = tid & 63;
    const int g = wave >> 2;                    // kt-half group
    const int lwave = wave & 3, lt = tid & 255;
    const int q32 = lane & 31, hi = lane >> 5;

    // XCD swizzle: dispatch D -> xcd = D%8; each XCD owns 4 whole heads.
    const int D = blockIdx.x;
    const int slot = D >> 3;
    const int bh = (D & 7) + ((slot & 3) << 3);
    const int qt = slot >> 2;
    const int m0 = qt * 128 + lwave * 32;
    const int b = bh >> 3, h = bh & 7;

    const short* qbase = qb + (size_t)bh * NSEQ * HD;
    const short* ksrc  = kb + (size_t)bh * 32 * 2048;    // 32 tiles x 4KB
    const short* vsrc  = vtb + (size_t)bh * 32 * 8192;   // 32 tiles x 16KB

    short8 qfrag[2];
    #pragma unroll
    for (int ks = 0; ks < 2; ks++)
        qfrag[ks] = *(const short8*)(qbase + (size_t)(m0 + q32) * 32 + ks * 16 + hi * 8);

    f32x16 o[4];
    #pragma unroll
    for (int dt = 0; dt < 4; dt++) o[dt] = zero16();
    float lrun = 0.f;

    auto STAGEV = [&](int buf, int t) {
        const short* vp = vsrc + (size_t)t * 8192 + lt * 8;
        #pragma unroll
        for (int p = 0; p < 4; p++)
            gload16(vp + p * 2048, &u.Vs[g][buf][p * 2048 + (lt >> 6) * 512]);
    };

    STAGEV(0, g * 16);
    __syncthreads();

    for (int t = 0; t < 16; t++) {
        const int cur = t & 1;
        const int kt = g * 16 + t;

        // K fragments: global -> registers (issued before V prefetch so the
        // QK^T waitcnt leaves the gload_lds queue untouched)
        short8 kf[4];
        #pragma unroll
        for (int f = 0; f < 4; f++)
            kf[f] = *(const short8*)(ksrc + (size_t)kt * 2048 + f * 512 + lane * 8);

        if (t < 15) STAGEV(cur ^ 1, kt + 1);    // prefetch under compute

        #pragma unroll
        for (int tt = 0; tt < 2; tt++) {
            // QK^T for this 32-key tile
            f32x16 a = zero16();
            __builtin_amdgcn_s_setprio(1);
            a = __builtin_amdgcn_mfma_f32_32x32x16_bf16(kf[2*tt+0], qfrag[0], a, 0, 0, 0);
            a = __builtin_amdgcn_mfma_f32_32x32x16_bf16(kf[2*tt+1], qfrag[1], a, 0, 0, 0);
            __builtin_amdgcn_s_setprio(0);

            // rolling: per 16-key kstep, exp2 -> pack -> pair-swap -> 4 PV MFMAs
            #pragma unroll
            for (int sx = 0; sx < 2; sx++) {
                float e0 = ex2(a[8*sx+0]), e1 = ex2(a[8*sx+1]);
                float e2 = ex2(a[8*sx+2]), e3 = ex2(a[8*sx+3]);
                float e4 = ex2(a[8*sx+4]), e5 = ex2(a[8*sx+5]);
                float e6 = ex2(a[8*sx+6]), e7 = ex2(a[8*sx+7]);
                lrun += ((e0 + e1) + (e2 + e3)) + ((e4 + e5) + (e6 + e7));
                uint32_t x0 = pkbf16(e0, e1), y0 = pkbf16(e4, e5);
                uint32_t x1 = pkbf16(e2, e3), y1 = pkbf16(e6, e7);
                asm("v_permlane32_swap_b32 %0, %1" : "+v"(x0), "+v"(y0));
                asm("v_permlane32_swap_b32 %0, %1" : "+v"(x1), "+v"(y1));
                u32x4 pv = { x0, x1, y0, y1 };
                short8 pf = __builtin_bit_cast(short8, pv);
                const int s = tt * 2 + sx;
                __builtin_amdgcn_s_setprio(1);
                #pragma unroll
                for (int dt = 0; dt < 4; dt++) {
                    short8 vf = *(const short8*)&u.Vs[g][cur][(dt * 4 + s) * 512 + lane * 8];
                    o[dt] = __builtin_amdgcn_mfma_f32_32x32x16_bf16(vf, pf, o[dt], 0, 0, 0);
                }
                __builtin_amdgcn_s_setprio(0);
            }
        }
        __syncthreads();                        // drains prefetch, guards buf reuse
    }

    // ----- exact partial merge (no-max softmax => plain sums), two phases -----
    float lpart = lrun + __shfl_xor(lrun, 32);  // per-q partial l, all lanes
    float linv = 0.f;
    size_t mg = (size_t)b * 2048 + m0 + q32;

    // phase 1: dt 0..1
    if (g == 1) {
        #pragma unroll
        for (int dt = 0; dt < 2; dt++)
            #pragma unroll
            for (int q4 = 0; q4 < 4; q4++) {
                f32x4 c = { o[dt][q4*4+0], o[dt][q4*4+1], o[dt][q4*4+2], o[dt][q4*4+3] };
                *(f32x4*)&u.m.om[lwave][dt * 4 + q4][lane][0] = c;
            }
        u.m.lm[lwave * 64 + lane] = lpart;
    }
    __syncthreads();
    if (g == 0) {
        #pragma unroll
        for (int dt = 0; dt < 2; dt++)
            #pragma unroll
            for (int q4 = 0; q4 < 4; q4++) {
                f32x4 c = *(const f32x4*)&u.m.om[lwave][dt * 4 + q4][lane][0];
                o[dt][q4*4+0] += c[0]; o[dt][q4*4+1] += c[1];
                o[dt][q4*4+2] += c[2]; o[dt][q4*4+3] += c[3];
            }
        float l = lpart + u.m.lm[lwave * 64 + lane];
        linv = 1.0f / l;

        short* xr = xob + mg * 256 + h * 32;
        #pragma unroll
        for (int gg = 0; gg < 4; gg++) {        // dt=0: scalar out
            short4v sv = { f2bf(o[0][4*gg+0] * linv), f2bf(o[0][4*gg+1] * linv),
                           f2bf(o[0][4*gg+2] * linv), f2bf(o[0][4*gg+3] * linv) };
            *(short4v*)(xr + gg * 8 + hi * 4) = sv;
        }
        short* vr = ovb + mg * 768 + h * 32;
        #pragma unroll
        for (int gg = 0; gg < 4; gg++) {        // dt=1: vec row 0
            short4v sv = { f2bf(o[1][4*gg+0] * linv), f2bf(o[1][4*gg+1] * linv),
                           f2bf(o[1][4*gg+2] * linv), f2bf(o[1][4*gg+3] * linv) };
            *(short4v*)(vr + gg * 8 + hi * 4) = sv;
        }
    }
    __syncthreads();
    // phase 2: dt 2..3
    if (g == 1) {
        #pragma unroll
        for (int dt = 2; dt < 4; dt++)
            #pragma unroll
            for (int q4 = 0; q4 < 4; q4++) {
                f32x4 c = { o[dt][q4*4+0], o[dt][q4*4+1], o[dt][q4*4+2], o[dt][q4*4+3] };
                *(f32x4*)&u.m.om[lwave][(dt - 2) * 4 + q4][lane][0] = c;
            }
    }
    __syncthreads();
    if (g == 0) {
        short* vr = ovb + mg * 768 + h * 32;
        #pragma unroll
        for (int dt = 2; dt < 4; dt++) {
            #pragma unroll
            for (int q4 = 0; q4 < 4; q4++) {
                f32x4 c = *(const f32x4*)&u.m.om[lwave][(dt - 2) * 4 + q4][lane][0];
                o[dt][q4*4+0] += c[0]; o[dt][q4*4+1] += c[1];
                o[dt][q4*4+2] += c[2]; o[dt][q4*4+3] += c[3];
            }
            #pragma unroll
            for (int gg = 0; gg < 4; gg++) {
                short4v sv = { f2bf(o[dt][4*gg+0] * linv), f2bf(o[dt][4*gg+1] * linv),
                               f2bf(o[dt][4*gg+2] * linv), f2bf(o[dt][4*gg+3] * linv) };
                *(short4v*)(vr + (dt - 1) * 256 + gg * 8 + hi * 4) = sv;
            }
        }
    }
}

// ---------------------------------------------------------------------------
// Kernel 4: MFMA epilogue GEMM + fused combine. grid 512, block 512 (8 waves).
// ---------------------------------------------------------------------------
__global__ __launch_bounds__(512, 4) void ogemm_kernel(
    const float* __restrict__ x, const short* __restrict__ xob,
    const short* __restrict__ invb,
    const float* __restrict__ dotb, const float* __restrict__ normb,
    const short* __restrict__ ovb,
    const short* __restrict__ Wob, const short* __restrict__ Wgb,
    const float* __restrict__ bo, const float* __restrict__ bg,
    float* __restrict__ out)
{
    __shared__ __align__(16) union {
        struct { short inv[16 * 520]; short xo[16 * 264]; } in;
        struct { short gate[16 * 264]; short o[16 * 776]; } ob;
    } u;
    const int tid = threadIdx.x;
    const int M0 = blockIdx.x * 16;

    #pragma unroll
    for (int l = 0; l < 2; l++) {
        int i = l * 512 + tid;
        int m = i >> 6, seg = i & 63;
        *(short8*)&u.in.inv[m * 520 + seg * 8] =
            *(const short8*)(invb + (size_t)(M0 + m) * 512 + seg * 8);
    }
    {
        int m = tid >> 5, seg = tid & 31;
        *(short8*)&u.in.xo[m * 264 + seg * 8] =
            *(const short8*)(xob + (size_t)(M0 + m) * 256 + seg * 8);
    }
    __syncthreads();

    const int wave = tid >> 6, lane = tid & 63;
    const int col = lane & 15, quad = lane >> 4;
    const int cg = wave * 32;       // this wave's Wg channel base (2 tiles)
    const int co = wave * 96;       // this wave's Wo channel base (6 tiles)

    f32x4 accg[2], acco[6];
    #pragma unroll
    for (int i = 0; i < 2; i++) accg[i] = (f32x4){0.f,0.f,0.f,0.f};
    #pragma unroll
    for (int i = 0; i < 6; i++) acco[i] = (f32x4){0.f,0.f,0.f,0.f};

    #pragma unroll
    for (int kk = 0; kk < 8; kk++) {
        // --- issue all loads for this phase (10 global + 3 LDS) ---
        short8 wg0 = *(const short8*)(Wgb + (size_t)(cg + col) * 512 + (2*kk) * 32 + quad * 8);
        short8 wg1 = *(const short8*)(Wgb + (size_t)(cg + 16 + col) * 512 + (2*kk) * 32 + quad * 8);
        short8 wg2 = *(const short8*)(Wgb + (size_t)(cg + col) * 512 + (2*kk+1) * 32 + quad * 8);
        short8 wg3 = *(const short8*)(Wgb + (size_t)(cg + 16 + col) * 512 + (2*kk+1) * 32 + quad * 8);
        short8 wo0 = *(const short8*)(Wob + (size_t)(co + 0*16 + col) * 256 + kk * 32 + quad * 8);
        short8 wo1 = *(const short8*)(Wob + (size_t)(co + 1*16 + col) * 256 + kk * 32 + quad * 8);
        short8 wo2 = *(const short8*)(Wob + (size_t)(co + 2*16 + col) * 256 + kk * 32 + quad * 8);
        short8 wo3 = *(const short8*)(Wob + (size_t)(co + 3*16 + col) * 256 + kk * 32 + quad * 8);
        short8 wo4 = *(const short8*)(Wob + (size_t)(co + 4*16 + col) * 256 + kk * 32 + quad * 8);
        short8 wo5 = *(const short8*)(Wob + (size_t)(co + 5*16 + col) * 256 + kk * 32 + quad * 8);
        short8 xg0 = *(const short8*)&u.in.inv[col * 520 + (2*kk) * 32 + quad * 8];
        short8 xg1 = *(const short8*)&u.in.inv[col * 520 + (2*kk+1) * 32 + quad * 8];
        short8 xoo = *(const short8*)&u.in.xo[col * 264 + kk * 32 + quad * 8];
        __builtin_amdgcn_sched_barrier(0);      // loads may NOT sink past here
        // --- consume ---
        accg[0] = __builtin_amdgcn_mfma_f32_16x16x32_bf16(wg0, xg0, accg[0], 0, 0, 0);
        accg[1] = __builtin_amdgcn_mfma_f32_16x16x32_bf16(wg1, xg0, accg[1], 0, 0, 0);
        accg[0] = __builtin_amdgcn_mfma_f32_16x16x32_bf16(wg2, xg1, accg[0], 0, 0, 0);
        accg[1] = __builtin_amdgcn_mfma_f32_16x16x32_bf16(wg3, xg1, accg[1], 0, 0, 0);
        acco[0] = __builtin_amdgcn_mfma_f32_16x16x32_bf16(wo0, xoo, acco[0], 0, 0, 0);
        acco[1] = __builtin_amdgcn_mfma_f32_16x16x32_bf16(wo1, xoo, acco[1], 0, 0, 0);
        acco[2] = __builtin_amdgcn_mfma_f32_16x16x32_bf16(wo2, xoo, acco[2], 0, 0, 0);
        acco[3] = __builtin_amdgcn_mfma_f32_16x16x32_bf16(wo3, xoo, acco[3], 0, 0, 0);
        acco[4] = __builtin_amdgcn_mfma_f32_16x16x32_bf16(wo4, xoo, acco[4], 0, 0, 0);
        acco[5] = __builtin_amdgcn_mfma_f32_16x16x32_bf16(wo5, xoo, acco[5], 0, 0, 0);
    }
    __syncthreads();

    #pragma unroll
    for (int i = 0; i < 2; i++) {
        int ch = cg + i * 16 + quad * 4;
        float4 bi = *(const float4*)&bg[ch];
        short4v s = { f2bf(1.f / (1.f + __expf(-(accg[i][0] + bi.x)))),
                      f2bf(1.f / (1.f + __expf(-(accg[i][1] + bi.y)))),
                      f2bf(1.f / (1.f + __expf(-(accg[i][2] + bi.z)))),
                      f2bf(1.f / (1.f + __expf(-(accg[i][3] + bi.w)))) };
        *(short4v*)&u.ob.gate[col * 264 + ch] = s;
    }
    #pragma unroll
    for (int i = 0; i < 6; i++) {
        int ch = co + i * 16 + quad * 4;
        float4 bi = *(const float4*)&bo[ch];
        short4v s = { f2bf(acco[i][0] + bi.x), f2bf(acco[i][1] + bi.y),
                      f2bf(acco[i][2] + bi.z), f2bf(acco[i][3] + bi.w) };
        *(short4v*)&u.ob.o[col * 776 + ch] = s;
    }
    __syncthreads();

    #pragma unroll
    for (int l = 0; l < 8; l++) {
        int idx4 = l * 512 + tid;
        int m = idx4 >> 8;
        int j = (idx4 & 255) * 4;
        size_t mg = (size_t)(M0 + m);
        if (j < 256) {
            float4 dv = *(const float4*)(dotb + mg * 256 + j);
            float4 nv = *(const float4*)(normb + mg * 256 + j);
            short4v o1 = *(short4v*)&u.ob.o[m * 776 + j];
            short4v o2 = *(short4v*)&u.ob.o[m * 776 + 256 + j];
            short4v o3 = *(short4v*)&u.ob.o[m * 776 + 512 + j];
            float4 r;
            r.x = dv.x * bf2f(o1[0]) + nv.x * bf2f(o2[0]) + bf2f(o3[0]);
            r.y = dv.y * bf2f(o1[1]) + nv.y * bf2f(o2[1]) + bf2f(o3[1]);
            r.z = dv.z * bf2f(o1[2]) + nv.z * bf2f(o2[2]) + bf2f(o3[2]);
            r.w = dv.w * bf2f(o1[3]) + nv.w * bf2f(o2[3]) + bf2f(o3[3]);
            *(float4*)(out + mg * 1024 + j) = r;
        } else {
            int c = (j >> 8) - 1, jj = j & 255;
            short4v g4 = *(short4v*)&u.ob.gate[m * 264 + jj];
            short4v av4 = *(const short4v*)(ovb + mg * 768 + c * 256 + jj);
            float4 xv = *(const float4*)(x + mg * 1024 + 256 + c * 256 + jj);
            float4 r = { bf2f(g4[0]) * bf2f(av4[0]) + xv.x, bf2f(g4[1]) * bf2f(av4[1]) + xv.y,
                         bf2f(g4[2]) * bf2f(av4[2]) + xv.z, bf2f(g4[3]) * bf2f(av4[3]) + xv.w };
            *(float4*)(out + mg * 1024 + j) = r;
        }
    }
}

// ---------------------------------------------------------------------------
extern "C" void kernel_launch(void* const* d_in, const int* in_sizes, int n_in,
                              void* d_out, int out_size, void* d_ws, size_t ws_size,
                              hipStream_t stream)
{
    const float* x    = (const float*)d_in[0];
    const float* Wq   = (const float*)d_in[1];
    const float* bq   = (const float*)d_in[2];
    const float* Wk   = (const float*)d_in[3];
    const float* bk   = (const float*)d_in[4];
    const float* Wv   = (const float*)d_in[5];
    const float* bv   = (const float*)d_in[6];
    const float* Wvec = (const float*)d_in[7];
    const float* Wo   = (const float*)d_in[8];
    const float* bo   = (const float*)d_in[9];
    const float* Wg   = (const float*)d_in[10];
    const float* bg   = (const float*)d_in[11];
    const float* adp  = (const float*)d_in[12];
    const float* anp  = (const float*)d_in[13];
    float* out = (float*)d_out;

    float* ws    = (float*)d_ws;
    short* qbf   = (short*)ws;
    short* kbf   = (short*)(ws + 1048576);
    short* vtb   = (short*)(ws + 2097152);
    float* dotb  = ws + 6291456;
    float* normb = ws + 8388608;
    short* xob   = (short*)(ws + 10485760);
    short* ovb   = (short*)(ws + 11534336);
    short* invb  = (short*)(ws + 17825792);
    short* Wqkvb = (short*)(ws + 19922944);
    float* bqkvs = ws + 20021248;
    short* Wvecb = (short*)(ws + 20022016);
    short* Wob   = (short*)(ws + 20087552);
    short* Wgb   = (short*)(ws + 20185856);

    wcvt_kernel<<<2560, 256, 0, stream>>>(Wq, Wk, Wv, Wvec, Wo, Wg, bq, bk, bv,
                                          adp, anp, Wqkvb, Wvecb, Wob, Wgb, bqkvs);
    qkv_kernel<<<768, 256, 0, stream>>>(x, Wqkvb, bqkvs, qbf, kbf, vtb);
    vec_kernel<<<512, 512, 0, stream>>>(x, Wvecb, dotb, invb, normb, vtb);
    attn_kernel<<<512, 512, 0, stream>>>(qbf, kbf, vtb, xob, ovb);
    ogemm_kernel<<<512, 512, 0, stream>>>(x, xob, invb, dotb, normb, ovb,
                                          Wob, Wgb, bo, bg, out);
}